// Round 8
// baseline (553.853 us; speedup 1.0000x reference)
//
#include <hip/hip_runtime.h>
#include <hip/hip_fp16.h>
#include <stdint.h>

// Problem constants
#define HIDDEN 1024
#define HEADS  16
#define DH     64
#define B_     2
#define L_     2048
#define M_TOT  (B_ * L_)          // 4096
#define ELEMS  (M_TOT * HIDDEN)   // 4,194,304
#define LOG2E  1.44269504088896340736f

typedef _Float16 f16;
typedef _Float16 f16x4 __attribute__((ext_vector_type(4)));
typedef _Float16 f16x8 __attribute__((ext_vector_type(8)));
typedef float    f32x4 __attribute__((ext_vector_type(4)));
typedef uint32_t u32;
typedef __attribute__((address_space(1))) u32 gu32;   // global ptr for global_load_lds
typedef __attribute__((address_space(3))) u32 su32;   // LDS ptr for global_load_lds

#define MFMA32(a, b, c) __builtin_amdgcn_mfma_f32_16x16x32_f16(a, b, c, 0, 0, 0)

// ---------------------------------------------------------------------------
// mfma layouts (verified):
//  16x16x32: A[m=lane&15][k=quad*8+j] (8 f16), B[k=quad*8+j][n=lane&15],
//            C/D row=quad*4+reg, col=lane&15
//  KEY TRICK (r10): key-PERMUTED S^T tiles put exp2(S^T) directly into the
//  MFMA32 B-operand layout — PV + denominator colsum all run as 16x16x32.
//  r17 (this round): attn v5 = v4 with the 8 waves split into 16
//  (1024-thread blocks): wave = (qg, key-QUARTER). Per-CU throughput terms
//  (LDS bytes, MFMA, exp2 per 128 keys) are IDENTICAL to v4; occupancy
//  doubles to 32 waves/CU = 8/SIMD (needs VGPR<=64, forced via
//  __launch_bounds__(1024,8); r7 compiled at exactly 64 with same state).
//  r7 counters showed ~40% un-hidden dependency-stall cycles at 4/SIMD.
//  Epilogue: 2-stage cross-wave tree reduction through dead K/V LDS.
// ---------------------------------------------------------------------------

// ---------------- f32 -> f16 pre-convert; weights packed [Wq;Wk;Wv;Wo] -----
__global__ __launch_bounds__(256)
void convert_f16(const float* __restrict__ query,
                 const float* __restrict__ Wq, const float* __restrict__ Wk,
                 const float* __restrict__ Wv, const float* __restrict__ Wo,
                 f16* __restrict__ Qh, f16* __restrict__ Wh)
{
    const int NQ4 = ELEMS / 4;              // 1048576 float4 units
    const int NW4 = (HIDDEN * HIDDEN) / 4;  // 262144 per weight
    const int total = NQ4 + 4 * NW4;
    for (int u = blockIdx.x * 256 + threadIdx.x; u < total; u += gridDim.x * 256) {
        float4 v; f16* dp;
        if (u < NQ4) {
            v = ((const float4*)query)[u];
            dp = Qh + (size_t)u * 4;
        } else {
            const int u2 = u - NQ4;
            const int w = u2 >> 18;            // NW4 = 2^18
            const int off = u2 & (NW4 - 1);
            const float* W = (w == 0) ? Wq : (w == 1) ? Wk : (w == 2) ? Wv : Wo;
            v = ((const float4*)W)[off];
            dp = Wh + (size_t)u2 * 4;          // stacked rows: q,k,v,o
        }
        f16x4 h = { (f16)v.x, (f16)v.y, (f16)v.z, (f16)v.w };
        *(f16x4*)dp = h;
    }
}

// ---------------- shared GEMM main loop: ring-3, counted vmcnt -------------
// LDS from the kernel's dynamic shared block (aliased across instantiations).
// SWAP=false: acc[i][j] = C[m][n]; SWAP=true: acc[i][j] = C^T.
template<int TM, int TN, bool SWAP>
__device__ __forceinline__
void gemm_loop(const f16* __restrict__ A, const f16* __restrict__ W,
               int mb, int nb, f32x4 (&acc)[TM / 32][TN / 32])
{
    extern __shared__ f16 smem[];            // 3*(TM+TN)*32 f16
    f16* As = smem;                          // [3][TM*32]
    f16* Bs = smem + 3 * TM * 32;            // [3][TN*32]

    const int tid  = threadIdx.x;
    const int lane = tid & 63;
    const int wave = tid >> 6;
    const int quad = lane >> 4;
    const int l16  = lane & 15;
    const int wm   = (wave >> 1) * (TM / 2);
    const int wn   = (wave & 1) * (TN / 2);

    constexpr int AISS = TM / 64;
    constexpr int BISS = TN / 64;
    int aoff[AISS], boff[BISS];
#pragma unroll
    for (int q = 0; q < AISS; q++) {
        const int p16 = (wave * AISS + q) * 64 + lane;
        const int r = p16 >> 2;
        const int c8 = (p16 & 3) ^ ((r >> 1) & 3);
        aoff[q] = (mb + r) * HIDDEN + c8 * 8;
    }
#pragma unroll
    for (int q = 0; q < BISS; q++) {
        const int p16 = (wave * BISS + q) * 64 + lane;
        const int r = p16 >> 2;
        const int c8 = (p16 & 3) ^ ((r >> 1) & 3);
        boff[q] = (nb + r) * HIDDEN + c8 * 8;
    }

    // prologue: stage tiles 0,1 into slots 0,1
#pragma unroll
    for (int p = 0; p < 2; p++) {
#pragma unroll
        for (int q = 0; q < AISS; q++)
            __builtin_amdgcn_global_load_lds((gu32*)&A[aoff[q] + p * 32],
                                             (su32*)&As[p * TM * 32 + (wave * AISS + q) * 512], 16, 0, 0);
#pragma unroll
        for (int q = 0; q < BISS; q++)
            __builtin_amdgcn_global_load_lds((gu32*)&W[boff[q] + p * 32],
                                             (su32*)&Bs[p * TN * 32 + (wave * BISS + q) * 512], 16, 0, 0);
    }

    int sl = 0;                                  // slot holding tile t
#pragma unroll 1
    for (int kb = 0; kb < HIDDEN; kb += 32) {
        // all but the newest LOADS (= tile t+1) retired -> tile t resident
        if constexpr (AISS + BISS == 4)
            asm volatile("s_waitcnt vmcnt(4)" ::: "memory");
        else
            asm volatile("s_waitcnt vmcnt(3)" ::: "memory");
        __builtin_amdgcn_s_barrier();            // publish tile t block-wide
        __builtin_amdgcn_sched_barrier(0);       // no motion across barrier

        // issue tile t+2 into slot (t+2)%3 == (t-1)%3 (wrap-to-0 harmless)
        const int nkb = (kb + 64 < HIDDEN) ? kb + 64 : 0;
        const int si  = (sl >= 1) ? sl - 1 : 2;
#pragma unroll
        for (int q = 0; q < AISS; q++)
            __builtin_amdgcn_global_load_lds((gu32*)&A[aoff[q] + nkb],
                                             (su32*)&As[si * TM * 32 + (wave * AISS + q) * 512], 16, 0, 0);
#pragma unroll
        for (int q = 0; q < BISS; q++)
            __builtin_amdgcn_global_load_lds((gu32*)&W[boff[q] + nkb],
                                             (su32*)&Bs[si * TN * 32 + (wave * BISS + q) * 512], 16, 0, 0);

        f16x8 af[TM / 32], bf[TN / 32];
#pragma unroll
        for (int i = 0; i < TM / 32; i++) {
            const int r = wm + i * 16 + l16;
            af[i] = *(const f16x8*)&As[sl * TM * 32 + r * 32 + (quad ^ ((r >> 1) & 3)) * 8];
        }
#pragma unroll
        for (int j = 0; j < TN / 32; j++) {
            const int r = wn + j * 16 + l16;
            bf[j] = *(const f16x8*)&Bs[sl * TN * 32 + r * 32 + (quad ^ ((r >> 1) & 3)) * 8];
        }
#pragma unroll
        for (int i = 0; i < TM / 32; i++)
#pragma unroll
            for (int j = 0; j < TN / 32; j++) {
                if constexpr (SWAP)
                    acc[i][j] = MFMA32(bf[j], af[i], acc[i][j]);
                else
                    acc[i][j] = MFMA32(af[i], bf[j], acc[i][j]);
            }

        sl = (sl + 1 == 3) ? 0 : sl + 1;
    }
    // drain wrap staging; epilogue only reads acc (no LDS reuse)
    asm volatile("s_waitcnt vmcnt(0)" ::: "memory");
}

// QKV projection: A = query f16 [4096][1024], W = packed [Wq;Wk;Wv] rows.
// Q/K blocks run SWAP=true -> lanes hold 4 consecutive dd -> f16x4 stores.
// V blocks run SWAP=false (V^T layout wants 4 consecutive l per lane).
__global__ __launch_bounds__(256)
void proj_qkv(const f16* __restrict__ A, const f16* __restrict__ W,
              const float* __restrict__ bq, const float* __restrict__ bk,
              const float* __restrict__ bv,
              f16* __restrict__ Qo, f16* __restrict__ Ko, f16* __restrict__ Vo)
{
    f32x4 acc[4][4] = {};
    const int mb = blockIdx.x * 128, nb = blockIdx.y * 128;
    const int nsel = nb >> 10;
    if (nsel < 2) gemm_loop<128, 128, true >(A, W, mb, nb, acc);
    else          gemm_loop<128, 128, false>(A, W, mb, nb, acc);

    const int lane = threadIdx.x & 63, wave = threadIdx.x >> 6;
    const int quad = lane >> 4, l16 = lane & 15;
    const int wm = (wave >> 1) * 64, wn = (wave & 1) * 64;
    const int nbase = nb & 1023;

    if (nsel < 2) {
        const float* bias = nsel ? bk : bq;
        f16* out = nsel ? Ko : Qo;
        const float scale = nsel ? 1.0f : 0.125f * LOG2E;
#pragma unroll
        for (int i = 0; i < 4; i++) {
            const int m = mb + wm + i * 16 + l16;        // SWAP: col = m
            const int b = m >> 11, l = m & (L_ - 1);
#pragma unroll
            for (int j = 0; j < 4; j++) {
                const int n0 = nbase + wn + j * 16 + quad * 4;   // SWAP: row = n
                const f32x4 bl4 = *(const f32x4*)&bias[n0];
                const int h = n0 >> 6, dd = n0 & 63;
                f16x4 pk;
#pragma unroll
                for (int r = 0; r < 4; r++)
                    pk[r] = (f16)((acc[i][j][r] + bl4[r]) * scale);
                *(f16x4*)&out[(((b * HEADS + h) * L_) + l) * DH + dd] = pk;
            }
        }
    } else {
#pragma unroll
        for (int i = 0; i < 4; i++)
#pragma unroll
            for (int j = 0; j < 4; j++) {
                const int n1 = nbase + wn + j * 16 + l16;
                const float bn = bv[n1];
                const int h = n1 >> 6, dd = n1 & 63;
                const int m0 = mb + wm + i * 16 + quad * 4;
                const int b = m0 >> 11, l0 = m0 & (L_ - 1);
                f16x4 pk;
#pragma unroll
                for (int r = 0; r < 4; r++) pk[r] = (f16)(acc[i][j][r] + bn);
                *(f16x4*)&Vo[((size_t)(b * HEADS + h) * DH + dd) * L_ + l0] = pk;
            }
    }
}

// Output projection: SWAP=true -> float4 stores.
__global__ __launch_bounds__(256)
void proj_out(const f16* __restrict__ A, const f16* __restrict__ W,
              const float* __restrict__ bo, float* __restrict__ out)
{
    f32x4 acc[4][2] = {};
    const int mb = blockIdx.x * 128, nb = blockIdx.y * 64;
    gemm_loop<128, 64, true>(A, W, mb, nb, acc);

    const int lane = threadIdx.x & 63, wave = threadIdx.x >> 6;
    const int quad = lane >> 4, l16 = lane & 15;
    const int wm = (wave >> 1) * 64, wn = (wave & 1) * 32;
#pragma unroll
    for (int i = 0; i < 4; i++) {
        const int m = mb + wm + i * 16 + l16;            // SWAP: col = m
#pragma unroll
        for (int j = 0; j < 2; j++) {
            const int n0 = nb + wn + j * 16 + quad * 4;  // SWAP: row = n
            const float4 b4 = *(const float4*)&bo[n0];
            float4 st;
            st.x = acc[i][j][0] + b4.x;
            st.y = acc[i][j][1] + b4.y;
            st.z = acc[i][j][2] + b4.z;
            st.w = acc[i][j][3] + b4.w;
            *(float4*)&out[m * HIDDEN + n0] = st;
        }
    }
}

// ---------------- flash attention v5: key-QUARTER split, 16-wave blocks ----
// Block = 1024 threads = 16 waves; 128 Q-rows/block; grid 512 (2 blk/CU,
// LDS 144 KB, 32 waves/CU = 8/SIMD — needs VGPR<=64, forced by
// __launch_bounds__(1024,8)). Wave w: qg=w>>2 (32 Q-rows), key-quarter
// g4=w&3 -> sub-tile cgi=g4>>1, half g=g4&1. Per wave per 128-key iter:
// 8 ds_read, 18 MFMA32, 16 exp2, 2 gload_lds — per-CU totals identical to
// v4; occupancy 2x. Staging: wave w stages sub-tile w>>3, slot w&7 (1 K +
// 1 V load/iter). End: 2-stage tree reduction of 4 key-quarter partials
// per qg through dead K/V LDS. XCD swizzle bijective. No-max softmax.
__global__ __launch_bounds__(1024, 8)
void attn(const f16* __restrict__ Q, const f16* __restrict__ K,
          const f16* __restrict__ Vt, const float* __restrict__ bias,
          f16* __restrict__ X)
{
    __shared__ f16 Ks[2][2][64 * 64];  // [buf][gi][key][dd]  32 KB
    __shared__ f16 Vs[2][2][64 * 64];  // [buf][gi][dd][key]  32 KB
    __shared__ float biasl[L_];        // bias * log2e        8 KB

    const int tid  = threadIdx.x;
    const int lane = tid & 63;
    const int wave = tid >> 6;         // 0..15
    const int quad = lane >> 4;
    const int l16  = lane & 15;
    const int qg   = wave >> 2;        // Q-row group 0..3
    const int g4   = wave & 3;         // key-quarter 0..3
    const int cgi  = g4 >> 1;          // compute sub-tile 0..1
    const int g    = g4 & 1;           // key-half within sub-tile
    const int sgi  = wave >> 3;        // staging sub-tile 0..1
    const int sw   = wave & 7;         // staging slot 0..7

    const int bid = (int)blockIdx.x;
    const int lb  = (bid & 7) * 64 + (bid >> 3);   // XCD-contiguous, bijective
    const int bh  = lb >> 4;                       // 0..31
    const int b   = bh >> 4, h = bh & 15;
    const int qrow0 = (lb & 15) * 128 + qg * 32;

    const f16* Qh  = Q  + (size_t)bh * L_ * DH;
    const f16* Kh  = K  + (size_t)bh * L_ * DH;
    const f16* Vth = Vt + (size_t)bh * DH * L_;

    {   // stage bias * log2e: 1024 float2 units, one per thread
        const float2 v2 = ((const float2*)(bias + b * L_))[tid];
        biasl[tid * 2 + 0] = v2.x * LOG2E;
        biasl[tid * 2 + 1] = v2.y * LOG2E;
    }

    // staging geometry (per 64-key sub-tile): unit p = sw*64 + lane;
    // row r = p>>3, w8 = p&7.
    // K source unit = w8 ^ (r&7) ^ (((r>>3)&1)<<2); V source unit = w8 ^ (r&7)
    int krow, kcol, vcol;
    {
        const int p = sw * 64 + lane;
        const int r = p >> 3;
        const int w8 = p & 7;
        krow = r;
        kcol = (w8 ^ (r & 7) ^ (((r >> 3) & 1) << 2)) * 8;
        vcol = (w8 ^ (r & 7)) * 8;
    }

    // Q fragments (B operand of S^T): qf[qtile][dd-half]
    f16x8 qf[2][2];
#pragma unroll
    for (int qt = 0; qt < 2; qt++)
#pragma unroll
        for (int hh = 0; hh < 2; hh++)
            qf[qt][hh] = *(const f16x8*)&Qh[(qrow0 + qt * 16 + l16) * DH + hh * 32 + quad * 8];

    // LDS read offsets for this wave's key-half g (within sub-tile cgi):
    // tile X rows rX = g*32 + (l16>>2)*8 + (l16&3); tile Y = rX+4.
    int koffX[2], koffY[2], voff[4];
    {
        const int rX = g * 32 + ((l16 >> 2) << 3) + (l16 & 3);
        const int rY = rX + 4;
        const int gkX = (rX & 7) ^ (((rX >> 3) & 1) << 2);
        const int gkY = (rY & 7) ^ (((rY >> 3) & 1) << 2);
#pragma unroll
        for (int hh = 0; hh < 2; hh++) {
            koffX[hh] = rX * 64 + (((hh * 4 + quad) ^ gkX) << 3);
            koffY[hh] = rY * 64 + (((hh * 4 + quad) ^ gkY) << 3);
        }
#pragma unroll
        for (int t = 0; t < 4; t++) {
            const int vr = t * 16 + l16;
            voff[t] = vr * 64 + (((g * 4 + quad) ^ (vr & 7)) << 3);
        }
    }

    // prologue: stage 128-key tile kb=0 into buf 0 (1 K + 1 V load per wave)
    __builtin_amdgcn_global_load_lds(
        (gu32*)(Kh + (size_t)(sgi * 64 + krow) * DH + kcol),
        (su32*)&Ks[0][sgi][sw * 512], 16, 0, 0);
    __builtin_amdgcn_global_load_lds(
        (gu32*)(Vth + (size_t)krow * L_ + sgi * 64 + vcol),
        (su32*)&Vs[0][sgi][sw * 512], 16, 0, 0);

    f32x4 o[2][4] = {};      // partial O^T (this key-quarter): [qtile][ddtile]
    f32x4 osum[2] = {};      // partial softmax denominator
    const f16x8 ones8 = { (f16)1.f, (f16)1.f, (f16)1.f, (f16)1.f,
                          (f16)1.f, (f16)1.f, (f16)1.f, (f16)1.f };
    __syncthreads();         // drains prologue staging + biasl

#pragma unroll 1
    for (int kb = 0; kb < L_; kb += 128) {
        const int buf = (kb >> 7) & 1;
        const int nkb = (kb + 128 < L_) ? kb + 128 : 0;   // last prefetch harmless

        // prefetch next 128-key tile into buf^1 (async, drained by end barrier)
        __builtin_amdgcn_global_load_lds(
            (gu32*)(Kh + (size_t)(nkb + sgi * 64 + krow) * DH + kcol),
            (su32*)&Ks[buf ^ 1][sgi][sw * 512], 16, 0, 0);
        __builtin_amdgcn_global_load_lds(
            (gu32*)(Vth + (size_t)krow * L_ + nkb + sgi * 64 + vcol),
            (su32*)&Vs[buf ^ 1][sgi][sw * 512], 16, 0, 0);

        // this wave's 32 keys (sub-tile cgi, half g): 8 reads, 18 MFMA
        const f16* Kb = &Ks[buf][cgi][0];
        const f16* Vb = &Vs[buf][cgi][0];
        const f16x8 kx0 = *(const f16x8*)&Kb[koffX[0]];
        const f16x8 kx1 = *(const f16x8*)&Kb[koffX[1]];
        const f16x8 ky0 = *(const f16x8*)&Kb[koffY[0]];
        const f16x8 ky1 = *(const f16x8*)&Kb[koffY[1]];
        f16x8 va[4];
#pragma unroll
        for (int t = 0; t < 4; t++)
            va[t] = *(const f16x8*)&Vb[voff[t]];
        const f32x4 blvX = *(const f32x4*)&biasl[kb + cgi * 64 + g * 32 + quad * 8];
        const f32x4 blvY = *(const f32x4*)&biasl[kb + cgi * 64 + g * 32 + quad * 8 + 4];

#pragma unroll
        for (int qt = 0; qt < 2; qt++) {
            f32x4 zx = blvX, zy = blvY;      // C = bias (per permuted key-row)
            zx = MFMA32(kx0, qf[qt][0], zx);
            zx = MFMA32(kx1, qf[qt][1], zx); // S^T[key=..+quad*8+r][q]+bias
            zy = MFMA32(ky0, qf[qt][0], zy);
            zy = MFMA32(ky1, qf[qt][1], zy); // S^T[key=..+quad*8+4+r][q]+bias
            const f16x8 pb = {
                (f16)__builtin_amdgcn_exp2f(zx[0]), (f16)__builtin_amdgcn_exp2f(zx[1]),
                (f16)__builtin_amdgcn_exp2f(zx[2]), (f16)__builtin_amdgcn_exp2f(zx[3]),
                (f16)__builtin_amdgcn_exp2f(zy[0]), (f16)__builtin_amdgcn_exp2f(zy[1]),
                (f16)__builtin_amdgcn_exp2f(zy[2]), (f16)__builtin_amdgcn_exp2f(zy[3]) };
            // P^T B-frag: k=quad*8+j over this wave's 32 keys
#pragma unroll
            for (int t = 0; t < 4; t++)
                o[qt][t] = MFMA32(va[t], pb, o[qt][t]);
            osum[qt] = MFMA32(ones8, pb, osum[qt]);   // denominator colsum
        }
        __syncthreads();   // staged tile ready; reads of buf done
    }
    // (final __syncthreads drained the wrap prefetch -> K/V LDS is dead)

    // 2-stage tree reduction of the 4 key-quarter partials per qg.
    // Slots: 4 KB per (wave,qt): [slot][ (t*4+r)*64 + lane ].
    // qt=0 -> Ks area (8192 floats = 8 slots), qt=1 -> Vs area.
    float* r0 = (float*)Ks;
    float* r1 = (float*)Vs;
    float s0 = osum[0][0], s1 = osum[1][0];

    // stage 1: odd quarters publish; even quarters accumulate. pair slot:
    const int s1slot = qg * 2 + cgi;
    if (g4 & 1) {
#pragma unroll
        for (int t = 0; t < 4; t++)
#pragma unroll
            for (int r = 0; r < 4; r++) {
                r0[s1slot * 1024 + (t * 4 + r) * 64 + lane] = o[0][t][r];
                r1[s1slot * 1024 + (t * 4 + r) * 64 + lane] = o[1][t][r];
            }
        biasl[s1slot * 128 + lane * 2 + 0] = s0;
        biasl[s1slot * 128 + lane * 2 + 1] = s1;
    }
    __syncthreads();
    if (!(g4 & 1)) {
#pragma unroll
        for (int t = 0; t < 4; t++)
#pragma unroll
            for (int r = 0; r < 4; r++) {
                o[0][t][r] += r0[s1slot * 1024 + (t * 4 + r) * 64 + lane];
                o[1][t][r] += r1[s1slot * 1024 + (t * 4 + r) * 64 + lane];
            }
        s0 += biasl[s1slot * 128 + lane * 2 + 0];
        s1 += biasl[s1slot * 128 + lane * 2 + 1];
    }
    __syncthreads();
    // stage 2: quarter 2 publishes (slots 0..3 now dead); quarter 0 merges.
    if (g4 == 2) {
#pragma unroll
        for (int t = 0; t < 4; t++)
#pragma unroll
            for (int r = 0; r < 4; r++) {
                r0[qg * 1024 + (t * 4 + r) * 64 + lane] = o[0][t][r];
                r1[qg * 1024 + (t * 4 + r) * 64 + lane] = o[1][t][r];
            }
        biasl[1024 + qg * 128 + lane * 2 + 0] = s0;
        biasl[1024 + qg * 128 + lane * 2 + 1] = s1;
    }
    __syncthreads();
    if (g4 == 0) {
#pragma unroll
        for (int t = 0; t < 4; t++)
#pragma unroll
            for (int r = 0; r < 4; r++) {
                o[0][t][r] += r0[qg * 1024 + (t * 4 + r) * 64 + lane];
                o[1][t][r] += r1[qg * 1024 + (t * 4 + r) * 64 + lane];
            }
        s0 += biasl[1024 + qg * 128 + lane * 2 + 0];
        s1 += biasl[1024 + qg * 128 + lane * 2 + 1];
#pragma unroll
        for (int qt = 0; qt < 2; qt++) {
            const float inv = 1.0f / (qt ? s1 : s0);
            const size_t qrow = (size_t)b * L_ + qrow0 + qt * 16 + l16;
#pragma unroll
            for (int t = 0; t < 4; t++) {
                f16x4 pk;
#pragma unroll
                for (int r = 0; r < 4; r++) pk[r] = (f16)(o[qt][t][r] * inv);
                *(f16x4*)&X[qrow * HIDDEN + h * DH + t * 16 + quad * 4] = pk;
            }
        }
    }
}

extern "C" void kernel_launch(void* const* d_in, const int* in_sizes, int n_in,
                              void* d_out, int out_size, void* d_ws, size_t ws_size,
                              hipStream_t stream)
{
    const float* query = (const float*)d_in[0];
    const float* bias  = (const float*)d_in[1];
    const float* Wq = (const float*)d_in[2]; const float* bq = (const float*)d_in[3];
    const float* Wk = (const float*)d_in[4]; const float* bk = (const float*)d_in[5];
    const float* Wv = (const float*)d_in[6]; const float* bv = (const float*)d_in[7];
    const float* Wo = (const float*)d_in[8]; const float* bo = (const float*)d_in[9];
    float* out = (float*)d_out;

    // workspace layout (40 MiB):
    f16* Wh = (f16*)d_ws;           // [4096][1024] packed f16 weights (q,k,v,o rows)
    f16* Qh = Wh + 4096 * 1024;     // [4096][1024] query f16; reused as Xf after qkv
    f16* Kf = Qh + ELEMS;           // [B,H,L,64]
    f16* Vf = Kf + ELEMS;           // [B,H,64,L] transposed
    f16* Qf = Vf + ELEMS;           // [B,H,L,64] scaled
    f16* Xf = Qh;                   // alias: query f16 dead after proj_qkv

    convert_f16<<<2048, 256, 0, stream>>>(query, Wq, Wk, Wv, Wo, Qh, Wh);
    // dynamic LDS: 3*(TM+TN)*32 f16 = 3*(128+128)*32*2 = 49152 B
    proj_qkv<<<dim3(32, 24), 256, 49152, stream>>>(Qh, Wh, bq, bk, bv, Qf, Kf, Vf);
    attn<<<512, 1024, 0, stream>>>(Qf, Kf, Vf, bias, Xf);
    // 3*(128+64)*32*2 = 36864 B
    proj_out<<<dim3(32, 16), 256, 36864, stream>>>(Xf, Wh + 3072 * 1024, bo, out);
}

// Round 9
// 450.876 us; speedup vs baseline: 1.2284x; 1.2284x over previous
//
#include <hip/hip_runtime.h>
#include <hip/hip_fp16.h>
#include <stdint.h>

// Problem constants
#define HIDDEN 1024
#define HEADS  16
#define DH     64
#define B_     2
#define L_     2048
#define M_TOT  (B_ * L_)          // 4096
#define ELEMS  (M_TOT * HIDDEN)   // 4,194,304
#define LOG2E  1.44269504088896340736f

typedef _Float16 f16;
typedef _Float16 f16x4 __attribute__((ext_vector_type(4)));
typedef _Float16 f16x8 __attribute__((ext_vector_type(8)));
typedef float    f32x4 __attribute__((ext_vector_type(4)));
typedef uint32_t u32;
typedef __attribute__((address_space(1))) u32 gu32;   // global ptr for global_load_lds
typedef __attribute__((address_space(3))) u32 su32;   // LDS ptr for global_load_lds

#define MFMA32(a, b, c) __builtin_amdgcn_mfma_f32_16x16x32_f16(a, b, c, 0, 0, 0)

// ---------------------------------------------------------------------------
// mfma layouts (verified):
//  16x16x32: A[m=lane&15][k=quad*8+j] (8 f16), B[k=quad*8+j][n=lane&15],
//            C/D row=quad*4+reg, col=lane&15
//  KEY TRICK (r10): key-PERMUTED S^T tiles put exp2(S^T) directly into the
//  MFMA32 B-operand layout — PV + denominator colsum all run as 16x16x32.
//  r18 (this round): attn v6. r8's v5 spilled catastrophically (forced
//  VGPR cap == exact current count -> allocator cliff, 1.7 GB scratch).
//  Also: grid 512 caps residency at 2 blk/CU regardless of LDS. v6 fixes
//  both: (1) V leaves LDS — PV A-frags read per-lane from global (L2-
//  resident, ~2.2 MB/XCD working set); LDS 40 KB -> 4 blk/CU possible;
//  (2) grid 1024 (64 Q-rows/block, 8 waves = qg x key-quarter, qt=2);
//  (3) launch_bounds(512,7): VGPR cap 73, headroom above v4's 64 (no
//  cliff). Per-CU MFMA/exp2 totals unchanged; LDS reads HALVED; waves/CU
//  16 -> 24-32.
// ---------------------------------------------------------------------------

// ---------------- f32 -> f16 pre-convert; weights packed [Wq;Wk;Wv;Wo] -----
__global__ __launch_bounds__(256)
void convert_f16(const float* __restrict__ query,
                 const float* __restrict__ Wq, const float* __restrict__ Wk,
                 const float* __restrict__ Wv, const float* __restrict__ Wo,
                 f16* __restrict__ Qh, f16* __restrict__ Wh)
{
    const int NQ4 = ELEMS / 4;              // 1048576 float4 units
    const int NW4 = (HIDDEN * HIDDEN) / 4;  // 262144 per weight
    const int total = NQ4 + 4 * NW4;
    for (int u = blockIdx.x * 256 + threadIdx.x; u < total; u += gridDim.x * 256) {
        float4 v; f16* dp;
        if (u < NQ4) {
            v = ((const float4*)query)[u];
            dp = Qh + (size_t)u * 4;
        } else {
            const int u2 = u - NQ4;
            const int w = u2 >> 18;            // NW4 = 2^18
            const int off = u2 & (NW4 - 1);
            const float* W = (w == 0) ? Wq : (w == 1) ? Wk : (w == 2) ? Wv : Wo;
            v = ((const float4*)W)[off];
            dp = Wh + (size_t)u2 * 4;          // stacked rows: q,k,v,o
        }
        f16x4 h = { (f16)v.x, (f16)v.y, (f16)v.z, (f16)v.w };
        *(f16x4*)dp = h;
    }
}

// ---------------- shared GEMM main loop: ring-3, counted vmcnt -------------
// LDS from the kernel's dynamic shared block (aliased across instantiations).
// SWAP=false: acc[i][j] = C[m][n]; SWAP=true: acc[i][j] = C^T.
template<int TM, int TN, bool SWAP>
__device__ __forceinline__
void gemm_loop(const f16* __restrict__ A, const f16* __restrict__ W,
               int mb, int nb, f32x4 (&acc)[TM / 32][TN / 32])
{
    extern __shared__ f16 smem[];            // 3*(TM+TN)*32 f16
    f16* As = smem;                          // [3][TM*32]
    f16* Bs = smem + 3 * TM * 32;            // [3][TN*32]

    const int tid  = threadIdx.x;
    const int lane = tid & 63;
    const int wave = tid >> 6;
    const int quad = lane >> 4;
    const int l16  = lane & 15;
    const int wm   = (wave >> 1) * (TM / 2);
    const int wn   = (wave & 1) * (TN / 2);

    constexpr int AISS = TM / 64;
    constexpr int BISS = TN / 64;
    int aoff[AISS], boff[BISS];
#pragma unroll
    for (int q = 0; q < AISS; q++) {
        const int p16 = (wave * AISS + q) * 64 + lane;
        const int r = p16 >> 2;
        const int c8 = (p16 & 3) ^ ((r >> 1) & 3);
        aoff[q] = (mb + r) * HIDDEN + c8 * 8;
    }
#pragma unroll
    for (int q = 0; q < BISS; q++) {
        const int p16 = (wave * BISS + q) * 64 + lane;
        const int r = p16 >> 2;
        const int c8 = (p16 & 3) ^ ((r >> 1) & 3);
        boff[q] = (nb + r) * HIDDEN + c8 * 8;
    }

    // prologue: stage tiles 0,1 into slots 0,1
#pragma unroll
    for (int p = 0; p < 2; p++) {
#pragma unroll
        for (int q = 0; q < AISS; q++)
            __builtin_amdgcn_global_load_lds((gu32*)&A[aoff[q] + p * 32],
                                             (su32*)&As[p * TM * 32 + (wave * AISS + q) * 512], 16, 0, 0);
#pragma unroll
        for (int q = 0; q < BISS; q++)
            __builtin_amdgcn_global_load_lds((gu32*)&W[boff[q] + p * 32],
                                             (su32*)&Bs[p * TN * 32 + (wave * BISS + q) * 512], 16, 0, 0);
    }

    int sl = 0;                                  // slot holding tile t
#pragma unroll 1
    for (int kb = 0; kb < HIDDEN; kb += 32) {
        // all but the newest LOADS (= tile t+1) retired -> tile t resident
        if constexpr (AISS + BISS == 4)
            asm volatile("s_waitcnt vmcnt(4)" ::: "memory");
        else
            asm volatile("s_waitcnt vmcnt(3)" ::: "memory");
        __builtin_amdgcn_s_barrier();            // publish tile t block-wide
        __builtin_amdgcn_sched_barrier(0);       // no motion across barrier

        // issue tile t+2 into slot (t+2)%3 == (t-1)%3 (wrap-to-0 harmless)
        const int nkb = (kb + 64 < HIDDEN) ? kb + 64 : 0;
        const int si  = (sl >= 1) ? sl - 1 : 2;
#pragma unroll
        for (int q = 0; q < AISS; q++)
            __builtin_amdgcn_global_load_lds((gu32*)&A[aoff[q] + nkb],
                                             (su32*)&As[si * TM * 32 + (wave * AISS + q) * 512], 16, 0, 0);
#pragma unroll
        for (int q = 0; q < BISS; q++)
            __builtin_amdgcn_global_load_lds((gu32*)&W[boff[q] + nkb],
                                             (su32*)&Bs[si * TN * 32 + (wave * BISS + q) * 512], 16, 0, 0);

        f16x8 af[TM / 32], bf[TN / 32];
#pragma unroll
        for (int i = 0; i < TM / 32; i++) {
            const int r = wm + i * 16 + l16;
            af[i] = *(const f16x8*)&As[sl * TM * 32 + r * 32 + (quad ^ ((r >> 1) & 3)) * 8];
        }
#pragma unroll
        for (int j = 0; j < TN / 32; j++) {
            const int r = wn + j * 16 + l16;
            bf[j] = *(const f16x8*)&Bs[sl * TN * 32 + r * 32 + (quad ^ ((r >> 1) & 3)) * 8];
        }
#pragma unroll
        for (int i = 0; i < TM / 32; i++)
#pragma unroll
            for (int j = 0; j < TN / 32; j++) {
                if constexpr (SWAP)
                    acc[i][j] = MFMA32(bf[j], af[i], acc[i][j]);
                else
                    acc[i][j] = MFMA32(af[i], bf[j], acc[i][j]);
            }

        sl = (sl + 1 == 3) ? 0 : sl + 1;
    }
    // drain wrap staging; epilogue only reads acc (no LDS reuse)
    asm volatile("s_waitcnt vmcnt(0)" ::: "memory");
}

// QKV projection: A = query f16 [4096][1024], W = packed [Wq;Wk;Wv] rows.
// Q/K blocks run SWAP=true -> lanes hold 4 consecutive dd -> f16x4 stores.
// V blocks run SWAP=false (V^T layout wants 4 consecutive l per lane).
__global__ __launch_bounds__(256)
void proj_qkv(const f16* __restrict__ A, const f16* __restrict__ W,
              const float* __restrict__ bq, const float* __restrict__ bk,
              const float* __restrict__ bv,
              f16* __restrict__ Qo, f16* __restrict__ Ko, f16* __restrict__ Vo)
{
    f32x4 acc[4][4] = {};
    const int mb = blockIdx.x * 128, nb = blockIdx.y * 128;
    const int nsel = nb >> 10;
    if (nsel < 2) gemm_loop<128, 128, true >(A, W, mb, nb, acc);
    else          gemm_loop<128, 128, false>(A, W, mb, nb, acc);

    const int lane = threadIdx.x & 63, wave = threadIdx.x >> 6;
    const int quad = lane >> 4, l16 = lane & 15;
    const int wm = (wave >> 1) * 64, wn = (wave & 1) * 64;
    const int nbase = nb & 1023;

    if (nsel < 2) {
        const float* bias = nsel ? bk : bq;
        f16* out = nsel ? Ko : Qo;
        const float scale = nsel ? 1.0f : 0.125f * LOG2E;
#pragma unroll
        for (int i = 0; i < 4; i++) {
            const int m = mb + wm + i * 16 + l16;        // SWAP: col = m
            const int b = m >> 11, l = m & (L_ - 1);
#pragma unroll
            for (int j = 0; j < 4; j++) {
                const int n0 = nbase + wn + j * 16 + quad * 4;   // SWAP: row = n
                const f32x4 bl4 = *(const f32x4*)&bias[n0];
                const int h = n0 >> 6, dd = n0 & 63;
                f16x4 pk;
#pragma unroll
                for (int r = 0; r < 4; r++)
                    pk[r] = (f16)((acc[i][j][r] + bl4[r]) * scale);
                *(f16x4*)&out[(((b * HEADS + h) * L_) + l) * DH + dd] = pk;
            }
        }
    } else {
#pragma unroll
        for (int i = 0; i < 4; i++)
#pragma unroll
            for (int j = 0; j < 4; j++) {
                const int n1 = nbase + wn + j * 16 + l16;
                const float bn = bv[n1];
                const int h = n1 >> 6, dd = n1 & 63;
                const int m0 = mb + wm + i * 16 + quad * 4;
                const int b = m0 >> 11, l0 = m0 & (L_ - 1);
                f16x4 pk;
#pragma unroll
                for (int r = 0; r < 4; r++) pk[r] = (f16)(acc[i][j][r] + bn);
                *(f16x4*)&Vo[((size_t)(b * HEADS + h) * DH + dd) * L_ + l0] = pk;
            }
    }
}

// Output projection: SWAP=true -> float4 stores.
__global__ __launch_bounds__(256)
void proj_out(const f16* __restrict__ A, const f16* __restrict__ W,
              const float* __restrict__ bo, float* __restrict__ out)
{
    f32x4 acc[4][2] = {};
    const int mb = blockIdx.x * 128, nb = blockIdx.y * 64;
    gemm_loop<128, 64, true>(A, W, mb, nb, acc);

    const int lane = threadIdx.x & 63, wave = threadIdx.x >> 6;
    const int quad = lane >> 4, l16 = lane & 15;
    const int wm = (wave >> 1) * 64, wn = (wave & 1) * 32;
#pragma unroll
    for (int i = 0; i < 4; i++) {
        const int m = mb + wm + i * 16 + l16;            // SWAP: col = m
#pragma unroll
        for (int j = 0; j < 2; j++) {
            const int n0 = nb + wn + j * 16 + quad * 4;  // SWAP: row = n
            const float4 b4 = *(const float4*)&bo[n0];
            float4 st;
            st.x = acc[i][j][0] + b4.x;
            st.y = acc[i][j][1] + b4.y;
            st.z = acc[i][j][2] + b4.z;
            st.w = acc[i][j][3] + b4.w;
            *(float4*)&out[m * HIDDEN + n0] = st;
        }
    }
}

// ---------------- flash attention v6: V-from-L2, 64-row blocks, grid 1024 --
// Block = 512 threads = 8 waves; 64 Q-rows/block (qg=wave>>2: 2 groups x
// 32 rows, qt=2); key-quarter g4=wave&3 (sub-tile cgi=g4>>1, half g=g4&1).
// K staged in LDS (32 KB dbuf, verified swizzle); V read per-lane from
// global (L2-resident: ~2.2 MB/XCD with XCD swizzle); bias in LDS (8 KB).
// LDS 40 KB -> up to 4 blk/CU; grid 1024 provides 4. launch_bounds(512,7):
// VGPR cap 73 (v4 fit 64 -> headroom, no r8-style cliff).
// Per CU at 4 blk: MFMA/exp2 totals = v4; LDS reads HALVED; waves 16->24-32.
// End: 2-stage tree reduction (4 quarters/qg) via dead Ks + biasl, with an
// extra barrier between stages (slot regions overlap). No-max softmax.
__global__ __launch_bounds__(512, 7)
void attn(const f16* __restrict__ Q, const f16* __restrict__ K,
          const f16* __restrict__ Vt, const float* __restrict__ bias,
          f16* __restrict__ X)
{
    __shared__ f16 Ks[2][2][64 * 64];  // [buf][gi][key][dd]  32 KB
    __shared__ float biasl[L_];        // bias * log2e        8 KB

    const int tid  = threadIdx.x;
    const int lane = tid & 63;
    const int wave = tid >> 6;         // 0..7
    const int quad = lane >> 4;
    const int l16  = lane & 15;
    const int qg   = wave >> 2;        // Q-row group 0..1
    const int g4   = wave & 3;         // key-quarter 0..3
    const int cgi  = g4 >> 1;          // sub-tile 0..1
    const int g    = g4 & 1;           // key-half within sub-tile

    const int bid = (int)blockIdx.x;
    const int lb  = (bid & 7) * 128 + (bid >> 3);  // XCD-contiguous, bijective
    const int bh  = lb >> 5;                       // 0..31
    const int b   = bh >> 4, h = bh & 15;
    const int qrow0 = (lb & 31) * 64 + qg * 32;

    const f16* Qh  = Q  + (size_t)bh * L_ * DH;
    const f16* Kh  = K  + (size_t)bh * L_ * DH;
    const f16* Vth = Vt + (size_t)bh * DH * L_;

    {   // stage bias * log2e: 512 float4 units, exactly one per thread
        const float4 v = ((const float4*)(bias + b * L_))[tid];
        biasl[tid * 4 + 0] = v.x * LOG2E;
        biasl[tid * 4 + 1] = v.y * LOG2E;
        biasl[tid * 4 + 2] = v.z * LOG2E;
        biasl[tid * 4 + 3] = v.w * LOG2E;
    }

    // K staging geometry (per 64-key sub-tile): unit p = wave*64 + lane;
    // row r = p>>3, w8 = p&7; source unit = w8 ^ (r&7) ^ (((r>>3)&1)<<2)
    int krow, kcol;
    {
        const int p = wave * 64 + lane;
        const int r = p >> 3;
        const int w8 = p & 7;
        krow = r;
        kcol = (w8 ^ (r & 7) ^ (((r >> 3) & 1) << 2)) * 8;
    }

    // Q fragments (B operand of S^T): qf[qtile][dd-half]
    f16x8 qf[2][2];
#pragma unroll
    for (int qt = 0; qt < 2; qt++)
#pragma unroll
        for (int hh = 0; hh < 2; hh++)
            qf[qt][hh] = *(const f16x8*)&Qh[(qrow0 + qt * 16 + l16) * DH + hh * 32 + quad * 8];

    // K LDS read offsets for key-half g (within sub-tile cgi):
    // tile X rows rX = g*32 + (l16>>2)*8 + (l16&3); tile Y = rX+4.
    int koffX[2], koffY[2];
    {
        const int rX = g * 32 + ((l16 >> 2) << 3) + (l16 & 3);
        const int rY = rX + 4;
        const int gkX = (rX & 7) ^ (((rX >> 3) & 1) << 2);
        const int gkY = (rY & 7) ^ (((rY >> 3) & 1) << 2);
#pragma unroll
        for (int hh = 0; hh < 2; hh++) {
            koffX[hh] = rX * 64 + (((hh * 4 + quad) ^ gkX) << 3);
            koffY[hh] = rY * 64 + (((hh * 4 + quad) ^ gkY) << 3);
        }
    }

    // V global offsets: A-frag V^T[dd = t*16+l16][key = base + quad*8 .. +7]
    int voffg[4];
#pragma unroll
    for (int t = 0; t < 4; t++)
        voffg[t] = (t * 16 + l16) * L_ + cgi * 64 + g * 32 + quad * 8;

    // prologue: stage K tile kb=0 into buf 0 (2 sub-tile loads per wave)
#pragma unroll
    for (int gi = 0; gi < 2; gi++)
        __builtin_amdgcn_global_load_lds(
            (gu32*)(Kh + (size_t)(gi * 64 + krow) * DH + kcol),
            (su32*)&Ks[0][gi][wave * 512], 16, 0, 0);

    f32x4 o[2][4] = {};      // partial O^T (this key-quarter): [qtile][ddtile]
    f32x4 osum[2] = {};      // partial softmax denominator
    const f16x8 ones8 = { (f16)1.f, (f16)1.f, (f16)1.f, (f16)1.f,
                          (f16)1.f, (f16)1.f, (f16)1.f, (f16)1.f };
    __syncthreads();         // drains prologue staging + biasl

#pragma unroll 1
    for (int kb = 0; kb < L_; kb += 128) {
        const int buf = (kb >> 7) & 1;
        const int nkb = (kb + 128 < L_) ? kb + 128 : 0;   // last prefetch harmless

        // prefetch next K tile into buf^1 (async, drained by end barrier)
#pragma unroll
        for (int gi = 0; gi < 2; gi++)
            __builtin_amdgcn_global_load_lds(
                (gu32*)(Kh + (size_t)(nkb + gi * 64 + krow) * DH + kcol),
                (su32*)&Ks[buf ^ 1][gi][wave * 512], 16, 0, 0);

        // this wave's 32 keys (sub-tile cgi, half g): 4 K ds_reads,
        // 4 V global reads (L2), 18 MFMA
        const f16* Kb = &Ks[buf][cgi][0];
        const f16x8 kx0 = *(const f16x8*)&Kb[koffX[0]];
        const f16x8 kx1 = *(const f16x8*)&Kb[koffX[1]];
        const f16x8 ky0 = *(const f16x8*)&Kb[koffY[0]];
        const f16x8 ky1 = *(const f16x8*)&Kb[koffY[1]];
        f16x8 va[4];
#pragma unroll
        for (int t = 0; t < 4; t++)
            va[t] = *(const f16x8*)&Vth[voffg[t] + kb];
        const f32x4 blvX = *(const f32x4*)&biasl[kb + cgi * 64 + g * 32 + quad * 8];
        const f32x4 blvY = *(const f32x4*)&biasl[kb + cgi * 64 + g * 32 + quad * 8 + 4];

#pragma unroll
        for (int qt = 0; qt < 2; qt++) {
            f32x4 zx = blvX, zy = blvY;      // C = bias (per permuted key-row)
            zx = MFMA32(kx0, qf[qt][0], zx);
            zx = MFMA32(kx1, qf[qt][1], zx); // S^T[key=..+quad*8+r][q]+bias
            zy = MFMA32(ky0, qf[qt][0], zy);
            zy = MFMA32(ky1, qf[qt][1], zy); // S^T[key=..+quad*8+4+r][q]+bias
            const f16x8 pb = {
                (f16)__builtin_amdgcn_exp2f(zx[0]), (f16)__builtin_amdgcn_exp2f(zx[1]),
                (f16)__builtin_amdgcn_exp2f(zx[2]), (f16)__builtin_amdgcn_exp2f(zx[3]),
                (f16)__builtin_amdgcn_exp2f(zy[0]), (f16)__builtin_amdgcn_exp2f(zy[1]),
                (f16)__builtin_amdgcn_exp2f(zy[2]), (f16)__builtin_amdgcn_exp2f(zy[3]) };
            // P^T B-frag: k=quad*8+j over this wave's 32 keys
#pragma unroll
            for (int t = 0; t < 4; t++)
                o[qt][t] = MFMA32(va[t], pb, o[qt][t]);
            osum[qt] = MFMA32(ones8, pb, osum[qt]);   // denominator colsum
        }
        __syncthreads();   // staged K tile ready; reads of buf done
    }
    // (final __syncthreads drained the wrap prefetch -> Ks LDS is dead)

    // tree reduction of 4 key-quarter partials per qg via dead Ks + biasl.
    // Slot layout: r0[slot*2048 + (qt*16 + t*4 + r)*64 + lane], slot size
    // 2048 f32; Ks = 8192 f32 = 4 slots. osum via biasl (dead after loop).
    float* r0 = (float*)Ks;
    float s0 = osum[0][0], s1 = osum[1][0];
    const int s1slot = qg * 2 + cgi;

    // stage 1: odd quarters publish
    if (g4 & 1) {
#pragma unroll
        for (int qt = 0; qt < 2; qt++)
#pragma unroll
            for (int t = 0; t < 4; t++)
#pragma unroll
                for (int rr = 0; rr < 4; rr++)
                    r0[s1slot * 2048 + (qt * 16 + t * 4 + rr) * 64 + lane] = o[qt][t][rr];
        biasl[s1slot * 128 + lane * 2 + 0] = s0;
        biasl[s1slot * 128 + lane * 2 + 1] = s1;
    }
    __syncthreads();
    // stage 1 accumulate (even quarters)
    if (!(g4 & 1)) {
#pragma unroll
        for (int qt = 0; qt < 2; qt++)
#pragma unroll
            for (int t = 0; t < 4; t++)
#pragma unroll
                for (int rr = 0; rr < 4; rr++)
                    o[qt][t][rr] += r0[s1slot * 2048 + (qt * 16 + t * 4 + rr) * 64 + lane];
        s0 += biasl[s1slot * 128 + lane * 2 + 0];
        s1 += biasl[s1slot * 128 + lane * 2 + 1];
    }
    __syncthreads();   // stage-1 reads done before stage-2 overwrites slots
    // stage 2: quarter 2 publishes (slots qg*1 region; distinct osum area)
    if (g4 == 2) {
#pragma unroll
        for (int qt = 0; qt < 2; qt++)
#pragma unroll
            for (int t = 0; t < 4; t++)
#pragma unroll
                for (int rr = 0; rr < 4; rr++)
                    r0[qg * 2048 + (qt * 16 + t * 4 + rr) * 64 + lane] = o[qt][t][rr];
        biasl[1024 + qg * 128 + lane * 2 + 0] = s0;
        biasl[1024 + qg * 128 + lane * 2 + 1] = s1;
    }
    __syncthreads();
    // stage 2 merge + store (quarter 0)
    if (g4 == 0) {
#pragma unroll
        for (int qt = 0; qt < 2; qt++)
#pragma unroll
            for (int t = 0; t < 4; t++)
#pragma unroll
                for (int rr = 0; rr < 4; rr++)
                    o[qt][t][rr] += r0[qg * 2048 + (qt * 16 + t * 4 + rr) * 64 + lane];
        s0 += biasl[1024 + qg * 128 + lane * 2 + 0];
        s1 += biasl[1024 + qg * 128 + lane * 2 + 1];
#pragma unroll
        for (int qt = 0; qt < 2; qt++) {
            const float inv = 1.0f / (qt ? s1 : s0);
            const size_t qrow = (size_t)b * L_ + qrow0 + qt * 16 + l16;
#pragma unroll
            for (int t = 0; t < 4; t++) {
                f16x4 pk;
#pragma unroll
                for (int rr = 0; rr < 4; rr++) pk[rr] = (f16)(o[qt][t][rr] * inv);
                *(f16x4*)&X[qrow * HIDDEN + h * DH + t * 16 + quad * 4] = pk;
            }
        }
    }
}

extern "C" void kernel_launch(void* const* d_in, const int* in_sizes, int n_in,
                              void* d_out, int out_size, void* d_ws, size_t ws_size,
                              hipStream_t stream)
{
    const float* query = (const float*)d_in[0];
    const float* bias  = (const float*)d_in[1];
    const float* Wq = (const float*)d_in[2]; const float* bq = (const float*)d_in[3];
    const float* Wk = (const float*)d_in[4]; const float* bk = (const float*)d_in[5];
    const float* Wv = (const float*)d_in[6]; const float* bv = (const float*)d_in[7];
    const float* Wo = (const float*)d_in[8]; const float* bo = (const float*)d_in[9];
    float* out = (float*)d_out;

    // workspace layout (40 MiB):
    f16* Wh = (f16*)d_ws;           // [4096][1024] packed f16 weights (q,k,v,o rows)
    f16* Qh = Wh + 4096 * 1024;     // [4096][1024] query f16; reused as Xf after qkv
    f16* Kf = Qh + ELEMS;           // [B,H,L,64]
    f16* Vf = Kf + ELEMS;           // [B,H,64,L] transposed
    f16* Qf = Vf + ELEMS;           // [B,H,L,64] scaled
    f16* Xf = Qh;                   // alias: query f16 dead after proj_qkv

    convert_f16<<<2048, 256, 0, stream>>>(query, Wq, Wk, Wv, Wo, Qh, Wh);
    // dynamic LDS: 3*(TM+TN)*32 f16 = 3*(128+128)*32*2 = 49152 B
    proj_qkv<<<dim3(32, 24), 256, 49152, stream>>>(Qh, Wh, bq, bk, bv, Qf, Kf, Vf);
    attn<<<1024, 512, 0, stream>>>(Qf, Kf, Vf, bias, Xf);
    // 3*(128+64)*32*2 = 36864 B
    proj_out<<<dim3(32, 16), 256, 36864, stream>>>(Xf, Wh + 3072 * 1024, bo, out);
}

// Round 10
// 222.054 us; speedup vs baseline: 2.4942x; 2.0305x over previous
//
#include <hip/hip_runtime.h>
#include <hip/hip_fp16.h>
#include <stdint.h>

// Problem constants
#define HIDDEN 1024
#define HEADS  16
#define DH     64
#define B_     2
#define L_     2048
#define M_TOT  (B_ * L_)          // 4096
#define ELEMS  (M_TOT * HIDDEN)   // 4,194,304
#define LOG2E  1.44269504088896340736f

typedef _Float16 f16;
typedef _Float16 f16x4 __attribute__((ext_vector_type(4)));
typedef _Float16 f16x8 __attribute__((ext_vector_type(8)));
typedef float    f32x4 __attribute__((ext_vector_type(4)));
typedef uint32_t u32;
typedef __attribute__((address_space(1))) u32 gu32;   // global ptr for global_load_lds
typedef __attribute__((address_space(3))) u32 su32;   // LDS ptr for global_load_lds

#define MFMA32(a, b, c) __builtin_amdgcn_mfma_f32_16x16x32_f16(a, b, c, 0, 0, 0)

// ---------------------------------------------------------------------------
// mfma layouts (verified):
//  16x16x32: A[m=lane&15][k=quad*8+j] (8 f16), B[k=quad*8+j][n=lane&15],
//            C/D row=quad*4+reg, col=lane&15
//  KEY TRICK (r10): key-PERMUTED S^T tiles put exp2(S^T) directly into the
//  MFMA32 B-operand layout — PV + denominator colsum all run as 16x16x32.
//  r19 (this round): v6 algorithm (V-from-L2, 64-row blocks, grid 1024 —
//  correct in r9, only spilled) with the register cap RELAXED:
//  launch_bounds(512,4) = cap 128. r9's (512,7) rounded to an effective
//  cap of 64 (8-wave blocks grant waves to SIMDs in PAIRS, so "min 7
//  waves/EU" rounds up to 8) -> v6's ~70 live regs spilled to scratch
//  (VGPR_Count 36, 1.17 GB traffic). Lesson: with 512-thread blocks the
//  2nd launch_bounds arg only usefully takes 2/4/6/8.
//  Expected: VGPR 70-90 -> 2-3 blk/CU, half the LDS reads of v4 (r2
//  showed LDS-read throughput binding at this occupancy).
// ---------------------------------------------------------------------------

// ---------------- f32 -> f16 pre-convert; weights packed [Wq;Wk;Wv;Wo] -----
__global__ __launch_bounds__(256)
void convert_f16(const float* __restrict__ query,
                 const float* __restrict__ Wq, const float* __restrict__ Wk,
                 const float* __restrict__ Wv, const float* __restrict__ Wo,
                 f16* __restrict__ Qh, f16* __restrict__ Wh)
{
    const int NQ4 = ELEMS / 4;              // 1048576 float4 units
    const int NW4 = (HIDDEN * HIDDEN) / 4;  // 262144 per weight
    const int total = NQ4 + 4 * NW4;
    for (int u = blockIdx.x * 256 + threadIdx.x; u < total; u += gridDim.x * 256) {
        float4 v; f16* dp;
        if (u < NQ4) {
            v = ((const float4*)query)[u];
            dp = Qh + (size_t)u * 4;
        } else {
            const int u2 = u - NQ4;
            const int w = u2 >> 18;            // NW4 = 2^18
            const int off = u2 & (NW4 - 1);
            const float* W = (w == 0) ? Wq : (w == 1) ? Wk : (w == 2) ? Wv : Wo;
            v = ((const float4*)W)[off];
            dp = Wh + (size_t)u2 * 4;          // stacked rows: q,k,v,o
        }
        f16x4 h = { (f16)v.x, (f16)v.y, (f16)v.z, (f16)v.w };
        *(f16x4*)dp = h;
    }
}

// ---------------- shared GEMM main loop: ring-3, counted vmcnt -------------
// LDS from the kernel's dynamic shared block (aliased across instantiations).
// SWAP=false: acc[i][j] = C[m][n]; SWAP=true: acc[i][j] = C^T.
template<int TM, int TN, bool SWAP>
__device__ __forceinline__
void gemm_loop(const f16* __restrict__ A, const f16* __restrict__ W,
               int mb, int nb, f32x4 (&acc)[TM / 32][TN / 32])
{
    extern __shared__ f16 smem[];            // 3*(TM+TN)*32 f16
    f16* As = smem;                          // [3][TM*32]
    f16* Bs = smem + 3 * TM * 32;            // [3][TN*32]

    const int tid  = threadIdx.x;
    const int lane = tid & 63;
    const int wave = tid >> 6;
    const int quad = lane >> 4;
    const int l16  = lane & 15;
    const int wm   = (wave >> 1) * (TM / 2);
    const int wn   = (wave & 1) * (TN / 2);

    constexpr int AISS = TM / 64;
    constexpr int BISS = TN / 64;
    int aoff[AISS], boff[BISS];
#pragma unroll
    for (int q = 0; q < AISS; q++) {
        const int p16 = (wave * AISS + q) * 64 + lane;
        const int r = p16 >> 2;
        const int c8 = (p16 & 3) ^ ((r >> 1) & 3);
        aoff[q] = (mb + r) * HIDDEN + c8 * 8;
    }
#pragma unroll
    for (int q = 0; q < BISS; q++) {
        const int p16 = (wave * BISS + q) * 64 + lane;
        const int r = p16 >> 2;
        const int c8 = (p16 & 3) ^ ((r >> 1) & 3);
        boff[q] = (nb + r) * HIDDEN + c8 * 8;
    }

    // prologue: stage tiles 0,1 into slots 0,1
#pragma unroll
    for (int p = 0; p < 2; p++) {
#pragma unroll
        for (int q = 0; q < AISS; q++)
            __builtin_amdgcn_global_load_lds((gu32*)&A[aoff[q] + p * 32],
                                             (su32*)&As[p * TM * 32 + (wave * AISS + q) * 512], 16, 0, 0);
#pragma unroll
        for (int q = 0; q < BISS; q++)
            __builtin_amdgcn_global_load_lds((gu32*)&W[boff[q] + p * 32],
                                             (su32*)&Bs[p * TN * 32 + (wave * BISS + q) * 512], 16, 0, 0);
    }

    int sl = 0;                                  // slot holding tile t
#pragma unroll 1
    for (int kb = 0; kb < HIDDEN; kb += 32) {
        // all but the newest LOADS (= tile t+1) retired -> tile t resident
        if constexpr (AISS + BISS == 4)
            asm volatile("s_waitcnt vmcnt(4)" ::: "memory");
        else
            asm volatile("s_waitcnt vmcnt(3)" ::: "memory");
        __builtin_amdgcn_s_barrier();            // publish tile t block-wide
        __builtin_amdgcn_sched_barrier(0);       // no motion across barrier

        // issue tile t+2 into slot (t+2)%3 == (t-1)%3 (wrap-to-0 harmless)
        const int nkb = (kb + 64 < HIDDEN) ? kb + 64 : 0;
        const int si  = (sl >= 1) ? sl - 1 : 2;
#pragma unroll
        for (int q = 0; q < AISS; q++)
            __builtin_amdgcn_global_load_lds((gu32*)&A[aoff[q] + nkb],
                                             (su32*)&As[si * TM * 32 + (wave * AISS + q) * 512], 16, 0, 0);
#pragma unroll
        for (int q = 0; q < BISS; q++)
            __builtin_amdgcn_global_load_lds((gu32*)&W[boff[q] + nkb],
                                             (su32*)&Bs[si * TN * 32 + (wave * BISS + q) * 512], 16, 0, 0);

        f16x8 af[TM / 32], bf[TN / 32];
#pragma unroll
        for (int i = 0; i < TM / 32; i++) {
            const int r = wm + i * 16 + l16;
            af[i] = *(const f16x8*)&As[sl * TM * 32 + r * 32 + (quad ^ ((r >> 1) & 3)) * 8];
        }
#pragma unroll
        for (int j = 0; j < TN / 32; j++) {
            const int r = wn + j * 16 + l16;
            bf[j] = *(const f16x8*)&Bs[sl * TN * 32 + r * 32 + (quad ^ ((r >> 1) & 3)) * 8];
        }
#pragma unroll
        for (int i = 0; i < TM / 32; i++)
#pragma unroll
            for (int j = 0; j < TN / 32; j++) {
                if constexpr (SWAP)
                    acc[i][j] = MFMA32(bf[j], af[i], acc[i][j]);
                else
                    acc[i][j] = MFMA32(af[i], bf[j], acc[i][j]);
            }

        sl = (sl + 1 == 3) ? 0 : sl + 1;
    }
    // drain wrap staging; epilogue only reads acc (no LDS reuse)
    asm volatile("s_waitcnt vmcnt(0)" ::: "memory");
}

// QKV projection: A = query f16 [4096][1024], W = packed [Wq;Wk;Wv] rows.
// Q/K blocks run SWAP=true -> lanes hold 4 consecutive dd -> f16x4 stores.
// V blocks run SWAP=false (V^T layout wants 4 consecutive l per lane).
__global__ __launch_bounds__(256)
void proj_qkv(const f16* __restrict__ A, const f16* __restrict__ W,
              const float* __restrict__ bq, const float* __restrict__ bk,
              const float* __restrict__ bv,
              f16* __restrict__ Qo, f16* __restrict__ Ko, f16* __restrict__ Vo)
{
    f32x4 acc[4][4] = {};
    const int mb = blockIdx.x * 128, nb = blockIdx.y * 128;
    const int nsel = nb >> 10;
    if (nsel < 2) gemm_loop<128, 128, true >(A, W, mb, nb, acc);
    else          gemm_loop<128, 128, false>(A, W, mb, nb, acc);

    const int lane = threadIdx.x & 63, wave = threadIdx.x >> 6;
    const int quad = lane >> 4, l16 = lane & 15;
    const int wm = (wave >> 1) * 64, wn = (wave & 1) * 64;
    const int nbase = nb & 1023;

    if (nsel < 2) {
        const float* bias = nsel ? bk : bq;
        f16* out = nsel ? Ko : Qo;
        const float scale = nsel ? 1.0f : 0.125f * LOG2E;
#pragma unroll
        for (int i = 0; i < 4; i++) {
            const int m = mb + wm + i * 16 + l16;        // SWAP: col = m
            const int b = m >> 11, l = m & (L_ - 1);
#pragma unroll
            for (int j = 0; j < 4; j++) {
                const int n0 = nbase + wn + j * 16 + quad * 4;   // SWAP: row = n
                const f32x4 bl4 = *(const f32x4*)&bias[n0];
                const int h = n0 >> 6, dd = n0 & 63;
                f16x4 pk;
#pragma unroll
                for (int r = 0; r < 4; r++)
                    pk[r] = (f16)((acc[i][j][r] + bl4[r]) * scale);
                *(f16x4*)&out[(((b * HEADS + h) * L_) + l) * DH + dd] = pk;
            }
        }
    } else {
#pragma unroll
        for (int i = 0; i < 4; i++)
#pragma unroll
            for (int j = 0; j < 4; j++) {
                const int n1 = nbase + wn + j * 16 + l16;
                const float bn = bv[n1];
                const int h = n1 >> 6, dd = n1 & 63;
                const int m0 = mb + wm + i * 16 + quad * 4;
                const int b = m0 >> 11, l0 = m0 & (L_ - 1);
                f16x4 pk;
#pragma unroll
                for (int r = 0; r < 4; r++) pk[r] = (f16)(acc[i][j][r] + bn);
                *(f16x4*)&Vo[((size_t)(b * HEADS + h) * DH + dd) * L_ + l0] = pk;
            }
    }
}

// Output projection: SWAP=true -> float4 stores.
__global__ __launch_bounds__(256)
void proj_out(const f16* __restrict__ A, const f16* __restrict__ W,
              const float* __restrict__ bo, float* __restrict__ out)
{
    f32x4 acc[4][2] = {};
    const int mb = blockIdx.x * 128, nb = blockIdx.y * 64;
    gemm_loop<128, 64, true>(A, W, mb, nb, acc);

    const int lane = threadIdx.x & 63, wave = threadIdx.x >> 6;
    const int quad = lane >> 4, l16 = lane & 15;
    const int wm = (wave >> 1) * 64, wn = (wave & 1) * 32;
#pragma unroll
    for (int i = 0; i < 4; i++) {
        const int m = mb + wm + i * 16 + l16;            // SWAP: col = m
#pragma unroll
        for (int j = 0; j < 2; j++) {
            const int n0 = nb + wn + j * 16 + quad * 4;  // SWAP: row = n
            const float4 b4 = *(const float4*)&bo[n0];
            float4 st;
            st.x = acc[i][j][0] + b4.x;
            st.y = acc[i][j][1] + b4.y;
            st.z = acc[i][j][2] + b4.z;
            st.w = acc[i][j][3] + b4.w;
            *(float4*)&out[m * HIDDEN + n0] = st;
        }
    }
}

// ---------------- flash attention v6b: V-from-L2, 64-row blocks, grid 1024 -
// Identical algorithm to r9 (verified correct there; absmax unchanged);
// only the register cap is relaxed: launch_bounds(512,4) -> VGPR cap 128,
// compiler free to use its natural ~70-90 -> no scratch. Residency then
// lands at 2-3 blk/CU from VGPR, with HALF v4's LDS reads (V from L2).
__global__ __launch_bounds__(512, 4)
void attn(const f16* __restrict__ Q, const f16* __restrict__ K,
          const f16* __restrict__ Vt, const float* __restrict__ bias,
          f16* __restrict__ X)
{
    __shared__ f16 Ks[2][2][64 * 64];  // [buf][gi][key][dd]  32 KB
    __shared__ float biasl[L_];        // bias * log2e        8 KB

    const int tid  = threadIdx.x;
    const int lane = tid & 63;
    const int wave = tid >> 6;         // 0..7
    const int quad = lane >> 4;
    const int l16  = lane & 15;
    const int qg   = wave >> 2;        // Q-row group 0..1
    const int g4   = wave & 3;         // key-quarter 0..3
    const int cgi  = g4 >> 1;          // sub-tile 0..1
    const int g    = g4 & 1;           // key-half within sub-tile

    const int bid = (int)blockIdx.x;
    const int lb  = (bid & 7) * 128 + (bid >> 3);  // XCD-contiguous, bijective
    const int bh  = lb >> 5;                       // 0..31
    const int b   = bh >> 4, h = bh & 15;
    const int qrow0 = (lb & 31) * 64 + qg * 32;

    const f16* Qh  = Q  + (size_t)bh * L_ * DH;
    const f16* Kh  = K  + (size_t)bh * L_ * DH;
    const f16* Vth = Vt + (size_t)bh * DH * L_;

    {   // stage bias * log2e: 512 float4 units, exactly one per thread
        const float4 v = ((const float4*)(bias + b * L_))[tid];
        biasl[tid * 4 + 0] = v.x * LOG2E;
        biasl[tid * 4 + 1] = v.y * LOG2E;
        biasl[tid * 4 + 2] = v.z * LOG2E;
        biasl[tid * 4 + 3] = v.w * LOG2E;
    }

    // K staging geometry (per 64-key sub-tile): unit p = wave*64 + lane;
    // row r = p>>3, w8 = p&7; source unit = w8 ^ (r&7) ^ (((r>>3)&1)<<2)
    int krow, kcol;
    {
        const int p = wave * 64 + lane;
        const int r = p >> 3;
        const int w8 = p & 7;
        krow = r;
        kcol = (w8 ^ (r & 7) ^ (((r >> 3) & 1) << 2)) * 8;
    }

    // Q fragments (B operand of S^T): qf[qtile][dd-half]
    f16x8 qf[2][2];
#pragma unroll
    for (int qt = 0; qt < 2; qt++)
#pragma unroll
        for (int hh = 0; hh < 2; hh++)
            qf[qt][hh] = *(const f16x8*)&Qh[(qrow0 + qt * 16 + l16) * DH + hh * 32 + quad * 8];

    // K LDS read offsets for key-half g (within sub-tile cgi):
    // tile X rows rX = g*32 + (l16>>2)*8 + (l16&3); tile Y = rX+4.
    int koffX[2], koffY[2];
    {
        const int rX = g * 32 + ((l16 >> 2) << 3) + (l16 & 3);
        const int rY = rX + 4;
        const int gkX = (rX & 7) ^ (((rX >> 3) & 1) << 2);
        const int gkY = (rY & 7) ^ (((rY >> 3) & 1) << 2);
#pragma unroll
        for (int hh = 0; hh < 2; hh++) {
            koffX[hh] = rX * 64 + (((hh * 4 + quad) ^ gkX) << 3);
            koffY[hh] = rY * 64 + (((hh * 4 + quad) ^ gkY) << 3);
        }
    }

    // V global offsets: A-frag V^T[dd = t*16+l16][key = base + quad*8 .. +7]
    int voffg[4];
#pragma unroll
    for (int t = 0; t < 4; t++)
        voffg[t] = (t * 16 + l16) * L_ + cgi * 64 + g * 32 + quad * 8;

    // prologue: stage K tile kb=0 into buf 0 (2 sub-tile loads per wave)
#pragma unroll
    for (int gi = 0; gi < 2; gi++)
        __builtin_amdgcn_global_load_lds(
            (gu32*)(Kh + (size_t)(gi * 64 + krow) * DH + kcol),
            (su32*)&Ks[0][gi][wave * 512], 16, 0, 0);

    f32x4 o[2][4] = {};      // partial O^T (this key-quarter): [qtile][ddtile]
    f32x4 osum[2] = {};      // partial softmax denominator
    const f16x8 ones8 = { (f16)1.f, (f16)1.f, (f16)1.f, (f16)1.f,
                          (f16)1.f, (f16)1.f, (f16)1.f, (f16)1.f };
    __syncthreads();         // drains prologue staging + biasl

#pragma unroll 1
    for (int kb = 0; kb < L_; kb += 128) {
        const int buf = (kb >> 7) & 1;
        const int nkb = (kb + 128 < L_) ? kb + 128 : 0;   // last prefetch harmless

        // prefetch next K tile into buf^1 (async, drained by end barrier)
#pragma unroll
        for (int gi = 0; gi < 2; gi++)
            __builtin_amdgcn_global_load_lds(
                (gu32*)(Kh + (size_t)(nkb + gi * 64 + krow) * DH + kcol),
                (su32*)&Ks[buf ^ 1][gi][wave * 512], 16, 0, 0);

        // this wave's 32 keys (sub-tile cgi, half g): 4 K ds_reads,
        // 4 V global reads (L2), 18 MFMA
        const f16* Kb = &Ks[buf][cgi][0];
        const f16x8 kx0 = *(const f16x8*)&Kb[koffX[0]];
        const f16x8 kx1 = *(const f16x8*)&Kb[koffX[1]];
        const f16x8 ky0 = *(const f16x8*)&Kb[koffY[0]];
        const f16x8 ky1 = *(const f16x8*)&Kb[koffY[1]];
        f16x8 va[4];
#pragma unroll
        for (int t = 0; t < 4; t++)
            va[t] = *(const f16x8*)&Vth[voffg[t] + kb];
        const f32x4 blvX = *(const f32x4*)&biasl[kb + cgi * 64 + g * 32 + quad * 8];
        const f32x4 blvY = *(const f32x4*)&biasl[kb + cgi * 64 + g * 32 + quad * 8 + 4];

#pragma unroll
        for (int qt = 0; qt < 2; qt++) {
            f32x4 zx = blvX, zy = blvY;      // C = bias (per permuted key-row)
            zx = MFMA32(kx0, qf[qt][0], zx);
            zx = MFMA32(kx1, qf[qt][1], zx); // S^T[key=..+quad*8+r][q]+bias
            zy = MFMA32(ky0, qf[qt][0], zy);
            zy = MFMA32(ky1, qf[qt][1], zy); // S^T[key=..+quad*8+4+r][q]+bias
            const f16x8 pb = {
                (f16)__builtin_amdgcn_exp2f(zx[0]), (f16)__builtin_amdgcn_exp2f(zx[1]),
                (f16)__builtin_amdgcn_exp2f(zx[2]), (f16)__builtin_amdgcn_exp2f(zx[3]),
                (f16)__builtin_amdgcn_exp2f(zy[0]), (f16)__builtin_amdgcn_exp2f(zy[1]),
                (f16)__builtin_amdgcn_exp2f(zy[2]), (f16)__builtin_amdgcn_exp2f(zy[3]) };
            // P^T B-frag: k=quad*8+j over this wave's 32 keys
#pragma unroll
            for (int t = 0; t < 4; t++)
                o[qt][t] = MFMA32(va[t], pb, o[qt][t]);
            osum[qt] = MFMA32(ones8, pb, osum[qt]);   // denominator colsum
        }
        __syncthreads();   // staged K tile ready; reads of buf done
    }
    // (final __syncthreads drained the wrap prefetch -> Ks LDS is dead)

    // tree reduction of 4 key-quarter partials per qg via dead Ks + biasl.
    // Slot layout: r0[slot*2048 + (qt*16 + t*4 + r)*64 + lane], slot size
    // 2048 f32; Ks = 8192 f32 = 4 slots. osum via biasl (dead after loop).
    float* r0 = (float*)Ks;
    float s0 = osum[0][0], s1 = osum[1][0];
    const int s1slot = qg * 2 + cgi;

    // stage 1: odd quarters publish
    if (g4 & 1) {
#pragma unroll
        for (int qt = 0; qt < 2; qt++)
#pragma unroll
            for (int t = 0; t < 4; t++)
#pragma unroll
                for (int rr = 0; rr < 4; rr++)
                    r0[s1slot * 2048 + (qt * 16 + t * 4 + rr) * 64 + lane] = o[qt][t][rr];
        biasl[s1slot * 128 + lane * 2 + 0] = s0;
        biasl[s1slot * 128 + lane * 2 + 1] = s1;
    }
    __syncthreads();
    // stage 1 accumulate (even quarters)
    if (!(g4 & 1)) {
#pragma unroll
        for (int qt = 0; qt < 2; qt++)
#pragma unroll
            for (int t = 0; t < 4; t++)
#pragma unroll
                for (int rr = 0; rr < 4; rr++)
                    o[qt][t][rr] += r0[s1slot * 2048 + (qt * 16 + t * 4 + rr) * 64 + lane];
        s0 += biasl[s1slot * 128 + lane * 2 + 0];
        s1 += biasl[s1slot * 128 + lane * 2 + 1];
    }
    __syncthreads();   // stage-1 reads done before stage-2 overwrites slots
    // stage 2: quarter 2 publishes (slots qg region; distinct osum area)
    if (g4 == 2) {
#pragma unroll
        for (int qt = 0; qt < 2; qt++)
#pragma unroll
            for (int t = 0; t < 4; t++)
#pragma unroll
                for (int rr = 0; rr < 4; rr++)
                    r0[qg * 2048 + (qt * 16 + t * 4 + rr) * 64 + lane] = o[qt][t][rr];
        biasl[1024 + qg * 128 + lane * 2 + 0] = s0;
        biasl[1024 + qg * 128 + lane * 2 + 1] = s1;
    }
    __syncthreads();
    // stage 2 merge + store (quarter 0)
    if (g4 == 0) {
#pragma unroll
        for (int qt = 0; qt < 2; qt++)
#pragma unroll
            for (int t = 0; t < 4; t++)
#pragma unroll
                for (int rr = 0; rr < 4; rr++)
                    o[qt][t][rr] += r0[qg * 2048 + (qt * 16 + t * 4 + rr) * 64 + lane];
        s0 += biasl[1024 + qg * 128 + lane * 2 + 0];
        s1 += biasl[1024 + qg * 128 + lane * 2 + 1];
#pragma unroll
        for (int qt = 0; qt < 2; qt++) {
            const float inv = 1.0f / (qt ? s1 : s0);
            const size_t qrow = (size_t)b * L_ + qrow0 + qt * 16 + l16;
#pragma unroll
            for (int t = 0; t < 4; t++) {
                f16x4 pk;
#pragma unroll
                for (int rr = 0; rr < 4; rr++) pk[rr] = (f16)(o[qt][t][rr] * inv);
                *(f16x4*)&X[qrow * HIDDEN + h * DH + t * 16 + quad * 4] = pk;
            }
        }
    }
}

extern "C" void kernel_launch(void* const* d_in, const int* in_sizes, int n_in,
                              void* d_out, int out_size, void* d_ws, size_t ws_size,
                              hipStream_t stream)
{
    const float* query = (const float*)d_in[0];
    const float* bias  = (const float*)d_in[1];
    const float* Wq = (const float*)d_in[2]; const float* bq = (const float*)d_in[3];
    const float* Wk = (const float*)d_in[4]; const float* bk = (const float*)d_in[5];
    const float* Wv = (const float*)d_in[6]; const float* bv = (const float*)d_in[7];
    const float* Wo = (const float*)d_in[8]; const float* bo = (const float*)d_in[9];
    float* out = (float*)d_out;

    // workspace layout (40 MiB):
    f16* Wh = (f16*)d_ws;           // [4096][1024] packed f16 weights (q,k,v,o rows)
    f16* Qh = Wh + 4096 * 1024;     // [4096][1024] query f16; reused as Xf after qkv
    f16* Kf = Qh + ELEMS;           // [B,H,L,64]
    f16* Vf = Kf + ELEMS;           // [B,H,64,L] transposed
    f16* Qf = Vf + ELEMS;           // [B,H,L,64] scaled
    f16* Xf = Qh;                   // alias: query f16 dead after proj_qkv

    convert_f16<<<2048, 256, 0, stream>>>(query, Wq, Wk, Wv, Wo, Qh, Wh);
    // dynamic LDS: 3*(TM+TN)*32 f16 = 3*(128+128)*32*2 = 49152 B
    proj_qkv<<<dim3(32, 24), 256, 49152, stream>>>(Qh, Wh, bq, bk, bv, Qf, Kf, Vf);
    attn<<<1024, 512, 0, stream>>>(Qf, Kf, Vf, bias, Xf);
    // 3*(128+64)*32*2 = 36864 B
    proj_out<<<dim3(32, 16), 256, 36864, stream>>>(Xf, Wh + 3072 * 1024, bo, out);
}

// Round 11
// 210.173 us; speedup vs baseline: 2.6352x; 1.0565x over previous
//
#include <hip/hip_runtime.h>
#include <hip/hip_fp16.h>
#include <stdint.h>

// Problem constants
#define HIDDEN 1024
#define HEADS  16
#define DH     64
#define B_     2
#define L_     2048
#define M_TOT  (B_ * L_)          // 4096
#define ELEMS  (M_TOT * HIDDEN)   // 4,194,304
#define LOG2E  1.44269504088896340736f

typedef _Float16 f16;
typedef _Float16 f16x4 __attribute__((ext_vector_type(4)));
typedef _Float16 f16x8 __attribute__((ext_vector_type(8)));
typedef float    f32x4 __attribute__((ext_vector_type(4)));
typedef uint32_t u32;
typedef __attribute__((address_space(1))) u32 gu32;   // global ptr for global_load_lds
typedef __attribute__((address_space(3))) u32 su32;   // LDS ptr for global_load_lds

#define MFMA32(a, b, c) __builtin_amdgcn_mfma_f32_16x16x32_f16(a, b, c, 0, 0, 0)

// ---------------------------------------------------------------------------
// r20: 3-kernel pipeline. (total - attn) was invariant 133-145 µs across 5
// GEMM structure variants -> ~40-60 µs is launch/gap overhead (~14/launch).
// convert_f16 ELIMINATED: qkv reads query/Wq/Wk/Wv f32, out reads Wo f32,
// converting during staging (reg-stage: float4 x2 -> cvt RNE -> ds_write;
// LDS stays f16; 2-buf __syncthreads loop — r4 proved sync-structure-
// insensitivity for these GEMMs). T14 split: loads at iter top, cvt+write
// after MFMA block (L2 latency hides under compute). Same (f16) casts as
// the old convert kernel -> bit-identical MFMA inputs.
// attn: r7-v4 verbatim (44 µs measured). r10's V-from-L2 refuted: per-lane
// global V loads share in-order vmcnt with global_load_lds prefetch -> the
// implicit wait for V drains the K prefetch every iter (88 µs). Never mix
// per-lane global loads with global_load_lds in a pipelined loop.
// ---------------------------------------------------------------------------

// ---------------- shared GEMM main loop: 2-buf, f32->f16 staging conversion -
// LDS from dynamic shared block (aliased across instantiations):
//   As = smem[0 .. 2*TM*32), Bs = smem[2*TM*32 ..)   (f16 elements)
// A32/B32: operand source is f32 -> reg-stage (load float4 x2, cvt, ds_write)
//          else f16 -> global_load_lds (no VGPR round-trip).
// SWAP=false: acc[i][j] = C[m][n] (row=quad*4+r is m, col=l16 is n)
// SWAP=true : acc[i][j] = C^T     (row=quad*4+r is n, col=l16 is m)
template<int TM, int TN, bool SWAP, bool A32, bool B32, typename TA, typename TB>
__device__ __forceinline__
void gemm_loop(const TA* __restrict__ A, const TB* __restrict__ W,
               int mb, int nb, f32x4 (&acc)[TM / 32][TN / 32])
{
    extern __shared__ f16 smem[];            // 2*(TM+TN)*32 f16
    f16* As = smem;                          // [2][TM*32]
    f16* Bs = smem + 2 * TM * 32;            // [2][TN*32]

    const int tid  = threadIdx.x;
    const int lane = tid & 63;
    const int wave = tid >> 6;
    const int quad = lane >> 4;
    const int l16  = lane & 15;
    const int wm   = (wave >> 1) * (TM / 2);
    const int wn   = (wave & 1) * (TN / 2);

    constexpr int AISS = TM / 64;
    constexpr int BISS = TN / 64;
    int aoff[AISS], boff[BISS], au[AISS], bu[BISS];
#pragma unroll
    for (int q = 0; q < AISS; q++) {
        const int p16 = (wave * AISS + q) * 64 + lane;
        const int r = p16 >> 2;
        const int c8 = (p16 & 3) ^ ((r >> 1) & 3);
        aoff[q] = (mb + r) * HIDDEN + c8 * 8;
        au[q] = p16;
    }
#pragma unroll
    for (int q = 0; q < BISS; q++) {
        const int p16 = (wave * BISS + q) * 64 + lane;
        const int r = p16 >> 2;
        const int c8 = (p16 & 3) ^ ((r >> 1) & 3);
        boff[q] = (nb + r) * HIDDEN + c8 * 8;
        bu[q] = p16;
    }

    // prologue: stage tile kb=0 into buf 0 (combined load+cvt+write; one-time)
#pragma unroll
    for (int q = 0; q < AISS; q++) {
        if constexpr (A32) {
            const float4 u0 = *(const float4*)&A[aoff[q]];
            const float4 u1 = *(const float4*)&A[aoff[q] + 4];
            f16x8 hv = { (f16)u0.x, (f16)u0.y, (f16)u0.z, (f16)u0.w,
                         (f16)u1.x, (f16)u1.y, (f16)u1.z, (f16)u1.w };
            *(f16x8*)&As[au[q] * 8] = hv;
        } else {
            __builtin_amdgcn_global_load_lds((gu32*)&A[aoff[q]],
                                             (su32*)&As[(wave * AISS + q) * 512], 16, 0, 0);
        }
    }
#pragma unroll
    for (int q = 0; q < BISS; q++) {
        if constexpr (B32) {
            const float4 u0 = *(const float4*)&W[boff[q]];
            const float4 u1 = *(const float4*)&W[boff[q] + 4];
            f16x8 hv = { (f16)u0.x, (f16)u0.y, (f16)u0.z, (f16)u0.w,
                         (f16)u1.x, (f16)u1.y, (f16)u1.z, (f16)u1.w };
            *(f16x8*)&Bs[bu[q] * 8] = hv;
        } else {
            __builtin_amdgcn_global_load_lds((gu32*)&W[boff[q]],
                                             (su32*)&Bs[(wave * BISS + q) * 512], 16, 0, 0);
        }
    }
    __syncthreads();

#pragma unroll 1
    for (int kb = 0; kb < HIDDEN; kb += 32) {
        const int buf = (kb >> 5) & 1;
        const int nkb = (kb + 32 < HIDDEN) ? kb + 32 : 0;  // last prefetch harmless

        // (1) issue next-tile loads: f32 paths to regs, f16 paths direct-to-LDS.
        //     buf^1 was last read in iter t-1, sealed by its barrier.
        float4 fa0[AISS], fa1[AISS], fb0[BISS], fb1[BISS];
#pragma unroll
        for (int q = 0; q < AISS; q++) {
            if constexpr (A32) {
                fa0[q] = *(const float4*)&A[aoff[q] + nkb];
                fa1[q] = *(const float4*)&A[aoff[q] + nkb + 4];
            } else {
                __builtin_amdgcn_global_load_lds((gu32*)&A[aoff[q] + nkb],
                                                 (su32*)&As[(buf ^ 1) * TM * 32 + (wave * AISS + q) * 512], 16, 0, 0);
            }
        }
#pragma unroll
        for (int q = 0; q < BISS; q++) {
            if constexpr (B32) {
                fb0[q] = *(const float4*)&W[boff[q] + nkb];
                fb1[q] = *(const float4*)&W[boff[q] + nkb + 4];
            } else {
                __builtin_amdgcn_global_load_lds((gu32*)&W[boff[q] + nkb],
                                                 (su32*)&Bs[(buf ^ 1) * TN * 32 + (wave * BISS + q) * 512], 16, 0, 0);
            }
        }

        // (2) compute on buf
        f16x8 af[TM / 32], bf[TN / 32];
#pragma unroll
        for (int i = 0; i < TM / 32; i++) {
            const int r = wm + i * 16 + l16;
            af[i] = *(const f16x8*)&As[buf * TM * 32 + r * 32 + (quad ^ ((r >> 1) & 3)) * 8];
        }
#pragma unroll
        for (int j = 0; j < TN / 32; j++) {
            const int r = wn + j * 16 + l16;
            bf[j] = *(const f16x8*)&Bs[buf * TN * 32 + r * 32 + (quad ^ ((r >> 1) & 3)) * 8];
        }
#pragma unroll
        for (int i = 0; i < TM / 32; i++)
#pragma unroll
            for (int j = 0; j < TN / 32; j++) {
                if constexpr (SWAP)
                    acc[i][j] = MFMA32(bf[j], af[i], acc[i][j]);
                else
                    acc[i][j] = MFMA32(af[i], bf[j], acc[i][j]);
            }

        // (3) cvt + ds_write the f32-path tiles (loads completed under MFMAs)
        if constexpr (A32) {
#pragma unroll
            for (int q = 0; q < AISS; q++) {
                f16x8 hv = { (f16)fa0[q].x, (f16)fa0[q].y, (f16)fa0[q].z, (f16)fa0[q].w,
                             (f16)fa1[q].x, (f16)fa1[q].y, (f16)fa1[q].z, (f16)fa1[q].w };
                *(f16x8*)&As[(buf ^ 1) * TM * 32 + au[q] * 8] = hv;
            }
        }
        if constexpr (B32) {
#pragma unroll
            for (int q = 0; q < BISS; q++) {
                f16x8 hv = { (f16)fb0[q].x, (f16)fb0[q].y, (f16)fb0[q].z, (f16)fb0[q].w,
                             (f16)fb1[q].x, (f16)fb1[q].y, (f16)fb1[q].z, (f16)fb1[q].w };
                *(f16x8*)&Bs[(buf ^ 1) * TN * 32 + bu[q] * 8] = hv;
            }
        }
        __syncthreads();   // next tile published (vm + lgkm drained); buf reads done
    }
}

// QKV projection: A = query f32 [4096][1024], W = Wq/Wk/Wv f32 [1024][1024].
// Conversion fused into staging (convert_f16 kernel eliminated).
// Q/K blocks run SWAP=true -> lanes hold 4 consecutive dd -> f16x4 stores.
// V blocks run SWAP=false (V^T layout wants 4 consecutive l per lane).
__global__ __launch_bounds__(256)
void proj_qkv(const float* __restrict__ query,
              const float* __restrict__ Wq, const float* __restrict__ Wk,
              const float* __restrict__ Wv,
              const float* __restrict__ bq, const float* __restrict__ bk,
              const float* __restrict__ bv,
              f16* __restrict__ Qo, f16* __restrict__ Ko, f16* __restrict__ Vo)
{
    f32x4 acc[4][4] = {};
    const int mb = blockIdx.x * 128;
    const int nsel  = blockIdx.y >> 3;             // 0:Q 1:K 2:V
    const int nbase = (blockIdx.y & 7) * 128;
    const float* Wp = (nsel == 0) ? Wq : (nsel == 1) ? Wk : Wv;
    if (nsel < 2) gemm_loop<128, 128, true , true, true>(query, Wp, mb, nbase, acc);
    else          gemm_loop<128, 128, false, true, true>(query, Wp, mb, nbase, acc);

    const int lane = threadIdx.x & 63, wave = threadIdx.x >> 6;
    const int quad = lane >> 4, l16 = lane & 15;
    const int wm = (wave >> 1) * 64, wn = (wave & 1) * 64;

    if (nsel < 2) {
        const float* bias = nsel ? bk : bq;
        f16* out = nsel ? Ko : Qo;
        const float scale = nsel ? 1.0f : 0.125f * LOG2E;
#pragma unroll
        for (int i = 0; i < 4; i++) {
            const int m = mb + wm + i * 16 + l16;        // SWAP: col = m
            const int b = m >> 11, l = m & (L_ - 1);
#pragma unroll
            for (int j = 0; j < 4; j++) {
                const int n0 = nbase + wn + j * 16 + quad * 4;   // SWAP: row = n
                const f32x4 bl4 = *(const f32x4*)&bias[n0];
                const int h = n0 >> 6, dd = n0 & 63;
                f16x4 pk;
#pragma unroll
                for (int r = 0; r < 4; r++)
                    pk[r] = (f16)((acc[i][j][r] + bl4[r]) * scale);
                *(f16x4*)&out[(((b * HEADS + h) * L_) + l) * DH + dd] = pk;
            }
        }
    } else {
#pragma unroll
        for (int i = 0; i < 4; i++)
#pragma unroll
            for (int j = 0; j < 4; j++) {
                const int n1 = nbase + wn + j * 16 + l16;
                const float bn = bv[n1];
                const int h = n1 >> 6, dd = n1 & 63;
                const int m0 = mb + wm + i * 16 + quad * 4;
                const int b = m0 >> 11, l0 = m0 & (L_ - 1);
                f16x4 pk;
#pragma unroll
                for (int r = 0; r < 4; r++) pk[r] = (f16)(acc[i][j][r] + bn);
                *(f16x4*)&Vo[((size_t)(b * HEADS + h) * DH + dd) * L_ + l0] = pk;
            }
    }
}

// Output projection: A = Xf f16 (global_load_lds), B = Wo f32 (cvt staging).
// SWAP=true -> float4 stores.
__global__ __launch_bounds__(256)
void proj_out(const f16* __restrict__ A, const float* __restrict__ Wo,
              const float* __restrict__ bo, float* __restrict__ out)
{
    f32x4 acc[4][2] = {};
    const int mb = blockIdx.x * 128, nb = blockIdx.y * 64;
    gemm_loop<128, 64, true, false, true>(A, Wo, mb, nb, acc);

    const int lane = threadIdx.x & 63, wave = threadIdx.x >> 6;
    const int quad = lane >> 4, l16 = lane & 15;
    const int wm = (wave >> 1) * 64, wn = (wave & 1) * 32;
#pragma unroll
    for (int i = 0; i < 4; i++) {
        const int m = mb + wm + i * 16 + l16;            // SWAP: col = m
#pragma unroll
        for (int j = 0; j < 2; j++) {
            const int n0 = nb + wn + j * 16 + quad * 4;  // SWAP: row = n
            const float4 b4 = *(const float4*)&bo[n0];
            float4 st;
            st.x = acc[i][j][0] + b4.x;
            st.y = acc[i][j][1] + b4.y;
            st.z = acc[i][j][2] + b4.z;
            st.w = acc[i][j][3] + b4.w;
            *(float4*)&out[m * HIDDEN + n0] = st;
        }
    }
}

// ---------------- flash attention v4 (r7 verbatim — 44 µs measured) --------
// Block = 512 threads = 8 waves; 128 Q-rows/block; grid 512 (2 blk/CU,
// LDS 72 KB). Wave w: Q-group qg=w>>1 (rows qg*32..+31), key-half g=w&1.
// Each 128-key iteration = 2 sub-tiles (gi) of 64 keys with the verified
// [64][64] conflict-free layouts. Per wave per iter: 16 ds_read, 36 MFMA32,
// 32 exp2, 4 gload_lds, 2 barriers.
// End: key-half pairs sum partial O/osum through the dead K/V LDS buffers.
// XCD swizzle bijective (512%8==0). No-max softmax in exp2 domain.
__global__ __launch_bounds__(512, 4)
void attn(const f16* __restrict__ Q, const f16* __restrict__ K,
          const f16* __restrict__ Vt, const float* __restrict__ bias,
          f16* __restrict__ X)
{
    __shared__ f16 Ks[2][2][64 * 64];  // [buf][gi][key][dd]  8 KB each = 32 KB
    __shared__ f16 Vs[2][2][64 * 64];  // [buf][gi][dd][key]  8 KB each = 32 KB
    __shared__ float biasl[L_];        // bias * log2e        8 KB

    const int tid  = threadIdx.x;
    const int lane = tid & 63;
    const int wave = tid >> 6;         // 0..7
    const int quad = lane >> 4;
    const int l16  = lane & 15;
    const int qg   = wave >> 1;        // Q-row group 0..3
    const int g    = wave & 1;         // key-half 0..1 (within each 64-key gi)

    const int bid = (int)blockIdx.x;
    const int lb  = (bid & 7) * 64 + (bid >> 3);   // XCD-contiguous, bijective
    const int bh  = lb >> 4;                       // 0..31
    const int b   = bh >> 4, h = bh & 15;
    const int qrow0 = (lb & 15) * 128 + qg * 32;

    const f16* Qh  = Q  + (size_t)bh * L_ * DH;
    const f16* Kh  = K  + (size_t)bh * L_ * DH;
    const f16* Vth = Vt + (size_t)bh * DH * L_;

    {   // stage bias * log2e: 512 float4 units, exactly one per thread
        const float4 v = ((const float4*)(bias + b * L_))[tid];
        biasl[tid * 4 + 0] = v.x * LOG2E;
        biasl[tid * 4 + 1] = v.y * LOG2E;
        biasl[tid * 4 + 2] = v.z * LOG2E;
        biasl[tid * 4 + 3] = v.w * LOG2E;
    }

    // staging geometry (per 64-key sub-tile):
    // unit p = wave*64 + lane; row r = p>>3, w8 = p&7
    // K source unit = w8 ^ (r&7) ^ (((r>>3)&1)<<2); V source unit = w8 ^ (r&7)
    int krow, kcol, vcol;
    {
        const int p = wave * 64 + lane;
        const int r = p >> 3;
        const int w8 = p & 7;
        krow = r;
        kcol = (w8 ^ (r & 7) ^ (((r >> 3) & 1) << 2)) * 8;
        vcol = (w8 ^ (r & 7)) * 8;
    }

    // Q fragments (B operand of S^T): qf[qtile][dd-half]
    f16x8 qf[2][2];
#pragma unroll
    for (int qt = 0; qt < 2; qt++)
#pragma unroll
        for (int hh = 0; hh < 2; hh++)
            qf[qt][hh] = *(const f16x8*)&Qh[(qrow0 + qt * 16 + l16) * DH + hh * 32 + quad * 8];

    // LDS read offsets for this wave's fixed key-half g (within a sub-tile):
    // tile X rows rX = g*32 + (l16>>2)*8 + (l16&3); tile Y = rX+4.
    int koffX[2], koffY[2], voff[4];
    {
        const int rX = g * 32 + ((l16 >> 2) << 3) + (l16 & 3);
        const int rY = rX + 4;
        const int gkX = (rX & 7) ^ (((rX >> 3) & 1) << 2);
        const int gkY = (rY & 7) ^ (((rY >> 3) & 1) << 2);
#pragma unroll
        for (int hh = 0; hh < 2; hh++) {
            koffX[hh] = rX * 64 + (((hh * 4 + quad) ^ gkX) << 3);
            koffY[hh] = rY * 64 + (((hh * 4 + quad) ^ gkY) << 3);
        }
#pragma unroll
        for (int t = 0; t < 4; t++) {
            const int vr = t * 16 + l16;
            voff[t] = vr * 64 + (((g * 4 + quad) ^ (vr & 7)) << 3);
        }
    }

    // prologue: stage 128-key tile kb=0 into buf 0 (2 K + 2 V loads per wave)
#pragma unroll
    for (int gi = 0; gi < 2; gi++) {
        __builtin_amdgcn_global_load_lds(
            (gu32*)(Kh + (size_t)(gi * 64 + krow) * DH + kcol),
            (su32*)&Ks[0][gi][wave * 512], 16, 0, 0);
        __builtin_amdgcn_global_load_lds(
            (gu32*)(Vth + (size_t)krow * L_ + gi * 64 + vcol),
            (su32*)&Vs[0][gi][wave * 512], 16, 0, 0);
    }

    f32x4 o[2][4] = {};      // partial O^T (this key-half): [qtile][ddtile]
    f32x4 osum[2] = {};      // partial softmax denominator
    const f16x8 ones8 = { (f16)1.f, (f16)1.f, (f16)1.f, (f16)1.f,
                          (f16)1.f, (f16)1.f, (f16)1.f, (f16)1.f };
    __syncthreads();         // drains prologue staging + biasl

#pragma unroll 1
    for (int kb = 0; kb < L_; kb += 128) {
        const int buf = (kb >> 7) & 1;
        const int nkb = (kb + 128 < L_) ? kb + 128 : 0;   // last prefetch harmless

        // prefetch next 128-key tile into buf^1 (async, drained by end barrier)
#pragma unroll
        for (int gi = 0; gi < 2; gi++) {
            __builtin_amdgcn_global_load_lds(
                (gu32*)(Kh + (size_t)(nkb + gi * 64 + krow) * DH + kcol),
                (su32*)&Ks[buf ^ 1][gi][wave * 512], 16, 0, 0);
            __builtin_amdgcn_global_load_lds(
                (gu32*)(Vth + (size_t)krow * L_ + nkb + gi * 64 + vcol),
                (su32*)&Vs[buf ^ 1][gi][wave * 512], 16, 0, 0);
        }

        // two independent 64-key sub-tiles; this wave's key-half of each
#pragma unroll
        for (int gi = 0; gi < 2; gi++) {
            const f16* Kb = &Ks[buf][gi][0];
            const f16* Vb = &Vs[buf][gi][0];
            const f16x8 kx0 = *(const f16x8*)&Kb[koffX[0]];
            const f16x8 kx1 = *(const f16x8*)&Kb[koffX[1]];
            const f16x8 ky0 = *(const f16x8*)&Kb[koffY[0]];
            const f16x8 ky1 = *(const f16x8*)&Kb[koffY[1]];
            f16x8 va[4];
#pragma unroll
            for (int t = 0; t < 4; t++)
                va[t] = *(const f16x8*)&Vb[voff[t]];
            const f32x4 blvX = *(const f32x4*)&biasl[kb + gi * 64 + g * 32 + quad * 8];
            const f32x4 blvY = *(const f32x4*)&biasl[kb + gi * 64 + g * 32 + quad * 8 + 4];

#pragma unroll
            for (int qt = 0; qt < 2; qt++) {
                f32x4 zx = blvX, zy = blvY;      // C = bias (per permuted key-row)
                zx = MFMA32(kx0, qf[qt][0], zx);
                zx = MFMA32(kx1, qf[qt][1], zx); // S^T[key=..+quad*8+r][q]+bias
                zy = MFMA32(ky0, qf[qt][0], zy);
                zy = MFMA32(ky1, qf[qt][1], zy); // S^T[key=..+quad*8+4+r][q]+bias
                const f16x8 pb = {
                    (f16)__builtin_amdgcn_exp2f(zx[0]), (f16)__builtin_amdgcn_exp2f(zx[1]),
                    (f16)__builtin_amdgcn_exp2f(zx[2]), (f16)__builtin_amdgcn_exp2f(zx[3]),
                    (f16)__builtin_amdgcn_exp2f(zy[0]), (f16)__builtin_amdgcn_exp2f(zy[1]),
                    (f16)__builtin_amdgcn_exp2f(zy[2]), (f16)__builtin_amdgcn_exp2f(zy[3]) };
                // P^T B-frag: k=quad*8+j over this wave's 32 keys of sub-tile gi
#pragma unroll
                for (int t = 0; t < 4; t++)
                    o[qt][t] = MFMA32(va[t], pb, o[qt][t]);
                osum[qt] = MFMA32(ones8, pb, osum[qt]);   // denominator colsum
            }
        }
        __syncthreads();   // staged tile ready; reads of buf done
    }
    // (final __syncthreads drained the wrap prefetch -> K/V LDS is dead)

    // cross-wave reduction: key-half g=1 publishes partials via dead LDS.
    float* o0 = (float*)Ks;
    float* o1 = (float*)Vs;
    if (g) {
#pragma unroll
        for (int t = 0; t < 4; t++)
#pragma unroll
            for (int r = 0; r < 4; r++) {
                o0[(qg * 16 + t * 4 + r) * 64 + lane] = o[0][t][r];
                o1[(qg * 16 + t * 4 + r) * 64 + lane] = o[1][t][r];
            }
        biasl[(qg * 64 + lane) * 2 + 0] = osum[0][0];
        biasl[(qg * 64 + lane) * 2 + 1] = osum[1][0];
    }
    __syncthreads();
    if (!g) {
#pragma unroll
        for (int t = 0; t < 4; t++)
#pragma unroll
            for (int r = 0; r < 4; r++) {
                o[0][t][r] += o0[(qg * 16 + t * 4 + r) * 64 + lane];
                o[1][t][r] += o1[(qg * 16 + t * 4 + r) * 64 + lane];
            }
        const float s0 = osum[0][0] + biasl[(qg * 64 + lane) * 2 + 0];
        const float s1 = osum[1][0] + biasl[(qg * 64 + lane) * 2 + 1];
#pragma unroll
        for (int qt = 0; qt < 2; qt++) {
            const float inv = 1.0f / (qt ? s1 : s0);
            const size_t qrow = (size_t)b * L_ + qrow0 + qt * 16 + l16;
#pragma unroll
            for (int t = 0; t < 4; t++) {
                f16x4 pk;
#pragma unroll
                for (int r = 0; r < 4; r++) pk[r] = (f16)(o[qt][t][r] * inv);
                *(f16x4*)&X[qrow * HIDDEN + h * DH + t * 16 + quad * 4] = pk;
            }
        }
    }
}

extern "C" void kernel_launch(void* const* d_in, const int* in_sizes, int n_in,
                              void* d_out, int out_size, void* d_ws, size_t ws_size,
                              hipStream_t stream)
{
    const float* query = (const float*)d_in[0];
    const float* bias  = (const float*)d_in[1];
    const float* Wq = (const float*)d_in[2]; const float* bq = (const float*)d_in[3];
    const float* Wk = (const float*)d_in[4]; const float* bk = (const float*)d_in[5];
    const float* Wv = (const float*)d_in[6]; const float* bv = (const float*)d_in[7];
    const float* Wo = (const float*)d_in[8]; const float* bo = (const float*)d_in[9];
    float* out = (float*)d_out;

    // workspace layout (32 MiB used): no pre-converted copies anymore.
    f16* Kf = (f16*)d_ws;           // [B,H,L,64]
    f16* Vf = Kf + ELEMS;           // [B,H,64,L] transposed
    f16* Qf = Vf + ELEMS;           // [B,H,L,64] scaled
    f16* Xf = Qf + ELEMS;           // [4096][1024] attn output (f16)

    // dynamic LDS: 2*(TM+TN)*32 f16: qkv = 2*(128+128)*32*2 = 32768 B
    proj_qkv<<<dim3(32, 24), 256, 32768, stream>>>(query, Wq, Wk, Wv,
                                                   bq, bk, bv, Qf, Kf, Vf);
    attn<<<512, 512, 0, stream>>>(Qf, Kf, Vf, bias, Xf);
    // out = 2*(128+64)*32*2 = 24576 B
    proj_out<<<dim3(32, 16), 256, 24576, stream>>>(Xf, Wo, bo, out);
}

// Round 12
// 187.322 us; speedup vs baseline: 2.9567x; 1.1220x over previous
//
#include <hip/hip_runtime.h>
#include <hip/hip_fp16.h>
#include <stdint.h>

// Problem constants
#define HIDDEN 1024
#define HEADS  16
#define DH     64
#define B_     2
#define L_     2048
#define M_TOT  (B_ * L_)          // 4096
#define ELEMS  (M_TOT * HIDDEN)   // 4,194,304
#define LOG2E  1.44269504088896340736f

typedef _Float16 f16;
typedef _Float16 f16x4 __attribute__((ext_vector_type(4)));
typedef _Float16 f16x8 __attribute__((ext_vector_type(8)));
typedef float    f32x4 __attribute__((ext_vector_type(4)));
typedef uint32_t u32;
typedef __attribute__((address_space(1))) u32 gu32;   // global ptr for global_load_lds
typedef __attribute__((address_space(3))) u32 su32;   // LDS ptr for global_load_lds

#define MFMA32(a, b, c) __builtin_amdgcn_mfma_f32_16x16x32_f16(a, b, c, 0, 0, 0)

// ---------------------------------------------------------------------------
// r21: EXACT REVERT to r7 (best measured: 188.7 µs). Session ledger:
//  r7  = 188.7  (attn v4 44 µs; 4-kernel pipeline)           <- optimum
//  r8  = 553.9  (forced VGPR cap == current count -> spill cliff)
//  r9  = 450.9  ((512,7) launch_bounds rounds to cap 64 -> spill)
//  r10 = 222.1  (V-from-L2: per-lane global loads share in-order vmcnt
//                with global_load_lds prefetch -> per-iter drain, 88 µs)
//  r11 = 210.2  (f32-fused qkv: reg-staged loads consumed same-iter ->
//                L2 latency exposed per iter; 80-88 µs)
// Rules distilled: (1) never force a VGPR cap at the boundary; with
// 512-thread blocks launch_bounds' 2nd arg only takes 2/4/6/8 usefully.
// (2) never mix per-lane global loads with global_load_lds in a pipelined
// loop (one in-order vmcnt). (3) reg-staged operands under a per-iter
// barrier need >=2-tile pipeline depth. attn exploration closed at 44 µs
// (throughput terms fixed; LDS caps residency at 2 blk/CU).
// ---------------------------------------------------------------------------
// mfma layouts (verified):
//  16x16x32: A[m=lane&15][k=quad*8+j] (8 f16), B[k=quad*8+j][n=lane&15],
//            C/D row=quad*4+reg, col=lane&15
//  A and B operands have IDENTICAL per-lane structure -> swapping operand
//  order computes C^T for free: (a) attn's S^T/P^T register chain;
//  (b) GEMM epilogue coalescing — SWAP=true -> vector stores.
//  attn v4: KVBLK=128 as 2x64-key sub-tiles (gi) with verified
//  conflict-free swizzles; key-PERMUTED S^T tiles put exp2(S^T) directly
//  into the MFMA32 B-operand layout — PV + denominator colsum all 16x16x32.
// ---------------------------------------------------------------------------

// ---------------- f32 -> f16 pre-convert; weights packed [Wq;Wk;Wv;Wo] -----
__global__ __launch_bounds__(256)
void convert_f16(const float* __restrict__ query,
                 const float* __restrict__ Wq, const float* __restrict__ Wk,
                 const float* __restrict__ Wv, const float* __restrict__ Wo,
                 f16* __restrict__ Qh, f16* __restrict__ Wh)
{
    const int NQ4 = ELEMS / 4;              // 1048576 float4 units
    const int NW4 = (HIDDEN * HIDDEN) / 4;  // 262144 per weight
    const int total = NQ4 + 4 * NW4;
    for (int u = blockIdx.x * 256 + threadIdx.x; u < total; u += gridDim.x * 256) {
        float4 v; f16* dp;
        if (u < NQ4) {
            v = ((const float4*)query)[u];
            dp = Qh + (size_t)u * 4;
        } else {
            const int u2 = u - NQ4;
            const int w = u2 >> 18;            // NW4 = 2^18
            const int off = u2 & (NW4 - 1);
            const float* W = (w == 0) ? Wq : (w == 1) ? Wk : (w == 2) ? Wv : Wo;
            v = ((const float4*)W)[off];
            dp = Wh + (size_t)u2 * 4;          // stacked rows: q,k,v,o
        }
        f16x4 h = { (f16)v.x, (f16)v.y, (f16)v.z, (f16)v.w };
        *(f16x4*)dp = h;
    }
}

// ---------------- shared GEMM main loop: ring-3, counted vmcnt -------------
// LDS from the kernel's dynamic shared block (aliased across instantiations).
// SWAP=false: acc[i][j] = C[m][n]; SWAP=true: acc[i][j] = C^T.
template<int TM, int TN, bool SWAP>
__device__ __forceinline__
void gemm_loop(const f16* __restrict__ A, const f16* __restrict__ W,
               int mb, int nb, f32x4 (&acc)[TM / 32][TN / 32])
{
    extern __shared__ f16 smem[];            // 3*(TM+TN)*32 f16
    f16* As = smem;                          // [3][TM*32]
    f16* Bs = smem + 3 * TM * 32;            // [3][TN*32]

    const int tid  = threadIdx.x;
    const int lane = tid & 63;
    const int wave = tid >> 6;
    const int quad = lane >> 4;
    const int l16  = lane & 15;
    const int wm   = (wave >> 1) * (TM / 2);
    const int wn   = (wave & 1) * (TN / 2);

    constexpr int AISS = TM / 64;
    constexpr int BISS = TN / 64;
    int aoff[AISS], boff[BISS];
#pragma unroll
    for (int q = 0; q < AISS; q++) {
        const int p16 = (wave * AISS + q) * 64 + lane;
        const int r = p16 >> 2;
        const int c8 = (p16 & 3) ^ ((r >> 1) & 3);
        aoff[q] = (mb + r) * HIDDEN + c8 * 8;
    }
#pragma unroll
    for (int q = 0; q < BISS; q++) {
        const int p16 = (wave * BISS + q) * 64 + lane;
        const int r = p16 >> 2;
        const int c8 = (p16 & 3) ^ ((r >> 1) & 3);
        boff[q] = (nb + r) * HIDDEN + c8 * 8;
    }

    // prologue: stage tiles 0,1 into slots 0,1
#pragma unroll
    for (int p = 0; p < 2; p++) {
#pragma unroll
        for (int q = 0; q < AISS; q++)
            __builtin_amdgcn_global_load_lds((gu32*)&A[aoff[q] + p * 32],
                                             (su32*)&As[p * TM * 32 + (wave * AISS + q) * 512], 16, 0, 0);
#pragma unroll
        for (int q = 0; q < BISS; q++)
            __builtin_amdgcn_global_load_lds((gu32*)&W[boff[q] + p * 32],
                                             (su32*)&Bs[p * TN * 32 + (wave * BISS + q) * 512], 16, 0, 0);
    }

    int sl = 0;                                  // slot holding tile t
#pragma unroll 1
    for (int kb = 0; kb < HIDDEN; kb += 32) {
        // all but the newest LOADS (= tile t+1) retired -> tile t resident
        if constexpr (AISS + BISS == 4)
            asm volatile("s_waitcnt vmcnt(4)" ::: "memory");
        else
            asm volatile("s_waitcnt vmcnt(3)" ::: "memory");
        __builtin_amdgcn_s_barrier();            // publish tile t block-wide
        __builtin_amdgcn_sched_barrier(0);       // no motion across barrier

        // issue tile t+2 into slot (t+2)%3 == (t-1)%3 (wrap-to-0 harmless)
        const int nkb = (kb + 64 < HIDDEN) ? kb + 64 : 0;
        const int si  = (sl >= 1) ? sl - 1 : 2;
#pragma unroll
        for (int q = 0; q < AISS; q++)
            __builtin_amdgcn_global_load_lds((gu32*)&A[aoff[q] + nkb],
                                             (su32*)&As[si * TM * 32 + (wave * AISS + q) * 512], 16, 0, 0);
#pragma unroll
        for (int q = 0; q < BISS; q++)
            __builtin_amdgcn_global_load_lds((gu32*)&W[boff[q] + nkb],
                                             (su32*)&Bs[si * TN * 32 + (wave * BISS + q) * 512], 16, 0, 0);

        f16x8 af[TM / 32], bf[TN / 32];
#pragma unroll
        for (int i = 0; i < TM / 32; i++) {
            const int r = wm + i * 16 + l16;
            af[i] = *(const f16x8*)&As[sl * TM * 32 + r * 32 + (quad ^ ((r >> 1) & 3)) * 8];
        }
#pragma unroll
        for (int j = 0; j < TN / 32; j++) {
            const int r = wn + j * 16 + l16;
            bf[j] = *(const f16x8*)&Bs[sl * TN * 32 + r * 32 + (quad ^ ((r >> 1) & 3)) * 8];
        }
#pragma unroll
        for (int i = 0; i < TM / 32; i++)
#pragma unroll
            for (int j = 0; j < TN / 32; j++) {
                if constexpr (SWAP)
                    acc[i][j] = MFMA32(bf[j], af[i], acc[i][j]);
                else
                    acc[i][j] = MFMA32(af[i], bf[j], acc[i][j]);
            }

        sl = (sl + 1 == 3) ? 0 : sl + 1;
    }
    // drain wrap staging; epilogue only reads acc (no LDS reuse)
    asm volatile("s_waitcnt vmcnt(0)" ::: "memory");
}

// QKV projection: A = query f16 [4096][1024], W = packed [Wq;Wk;Wv] rows.
// Q/K blocks run SWAP=true -> lanes hold 4 consecutive dd -> f16x4 stores.
// V blocks run SWAP=false (V^T layout wants 4 consecutive l per lane).
__global__ __launch_bounds__(256)
void proj_qkv(const f16* __restrict__ A, const f16* __restrict__ W,
              const float* __restrict__ bq, const float* __restrict__ bk,
              const float* __restrict__ bv,
              f16* __restrict__ Qo, f16* __restrict__ Ko, f16* __restrict__ Vo)
{
    f32x4 acc[4][4] = {};
    const int mb = blockIdx.x * 128, nb = blockIdx.y * 128;
    const int nsel = nb >> 10;
    if (nsel < 2) gemm_loop<128, 128, true >(A, W, mb, nb, acc);
    else          gemm_loop<128, 128, false>(A, W, mb, nb, acc);

    const int lane = threadIdx.x & 63, wave = threadIdx.x >> 6;
    const int quad = lane >> 4, l16 = lane & 15;
    const int wm = (wave >> 1) * 64, wn = (wave & 1) * 64;
    const int nbase = nb & 1023;

    if (nsel < 2) {
        const float* bias = nsel ? bk : bq;
        f16* out = nsel ? Ko : Qo;
        const float scale = nsel ? 1.0f : 0.125f * LOG2E;
#pragma unroll
        for (int i = 0; i < 4; i++) {
            const int m = mb + wm + i * 16 + l16;        // SWAP: col = m
            const int b = m >> 11, l = m & (L_ - 1);
#pragma unroll
            for (int j = 0; j < 4; j++) {
                const int n0 = nbase + wn + j * 16 + quad * 4;   // SWAP: row = n
                const f32x4 bl4 = *(const f32x4*)&bias[n0];
                const int h = n0 >> 6, dd = n0 & 63;
                f16x4 pk;
#pragma unroll
                for (int r = 0; r < 4; r++)
                    pk[r] = (f16)((acc[i][j][r] + bl4[r]) * scale);
                *(f16x4*)&out[(((b * HEADS + h) * L_) + l) * DH + dd] = pk;
            }
        }
    } else {
#pragma unroll
        for (int i = 0; i < 4; i++)
#pragma unroll
            for (int j = 0; j < 4; j++) {
                const int n1 = nbase + wn + j * 16 + l16;
                const float bn = bv[n1];
                const int h = n1 >> 6, dd = n1 & 63;
                const int m0 = mb + wm + i * 16 + quad * 4;
                const int b = m0 >> 11, l0 = m0 & (L_ - 1);
                f16x4 pk;
#pragma unroll
                for (int r = 0; r < 4; r++) pk[r] = (f16)(acc[i][j][r] + bn);
                *(f16x4*)&Vo[((size_t)(b * HEADS + h) * DH + dd) * L_ + l0] = pk;
            }
    }
}

// Output projection: SWAP=true -> float4 stores.
__global__ __launch_bounds__(256)
void proj_out(const f16* __restrict__ A, const f16* __restrict__ W,
              const float* __restrict__ bo, float* __restrict__ out)
{
    f32x4 acc[4][2] = {};
    const int mb = blockIdx.x * 128, nb = blockIdx.y * 64;
    gemm_loop<128, 64, true>(A, W, mb, nb, acc);

    const int lane = threadIdx.x & 63, wave = threadIdx.x >> 6;
    const int quad = lane >> 4, l16 = lane & 15;
    const int wm = (wave >> 1) * 64, wn = (wave & 1) * 32;
#pragma unroll
    for (int i = 0; i < 4; i++) {
        const int m = mb + wm + i * 16 + l16;            // SWAP: col = m
#pragma unroll
        for (int j = 0; j < 2; j++) {
            const int n0 = nb + wn + j * 16 + quad * 4;  // SWAP: row = n
            const float4 b4 = *(const float4*)&bo[n0];
            float4 st;
            st.x = acc[i][j][0] + b4.x;
            st.y = acc[i][j][1] + b4.y;
            st.z = acc[i][j][2] + b4.z;
            st.w = acc[i][j][3] + b4.w;
            *(float4*)&out[m * HIDDEN + n0] = st;
        }
    }
}

// ---------------- flash attention v4: qt=2 + key-split, KVBLK=128 ----------
// Block = 512 threads = 8 waves; 128 Q-rows/block; grid 512 (2 blk/CU,
// LDS 72 KB). Wave w: Q-group qg=w>>1 (rows qg*32..+31), key-half g=w&1.
// Each 128-key iteration = 2 sub-tiles (gi) of 64 keys with the verified
// [64][64] conflict-free layouts. Per wave per iter: 16 ds_read, 36 MFMA32,
// 32 exp2, 4 gload_lds, 2 barriers.
// End: key-half pairs sum partial O/osum through the dead K/V LDS buffers.
// XCD swizzle bijective (512%8==0). No-max softmax in exp2 domain.
__global__ __launch_bounds__(512, 4)
void attn(const f16* __restrict__ Q, const f16* __restrict__ K,
          const f16* __restrict__ Vt, const float* __restrict__ bias,
          f16* __restrict__ X)
{
    __shared__ f16 Ks[2][2][64 * 64];  // [buf][gi][key][dd]  8 KB each = 32 KB
    __shared__ f16 Vs[2][2][64 * 64];  // [buf][gi][dd][key]  8 KB each = 32 KB
    __shared__ float biasl[L_];        // bias * log2e        8 KB

    const int tid  = threadIdx.x;
    const int lane = tid & 63;
    const int wave = tid >> 6;         // 0..7
    const int quad = lane >> 4;
    const int l16  = lane & 15;
    const int qg   = wave >> 1;        // Q-row group 0..3
    const int g    = wave & 1;         // key-half 0..1 (within each 64-key gi)

    const int bid = (int)blockIdx.x;
    const int lb  = (bid & 7) * 64 + (bid >> 3);   // XCD-contiguous, bijective
    const int bh  = lb >> 4;                       // 0..31
    const int b   = bh >> 4, h = bh & 15;
    const int qrow0 = (lb & 15) * 128 + qg * 32;

    const f16* Qh  = Q  + (size_t)bh * L_ * DH;
    const f16* Kh  = K  + (size_t)bh * L_ * DH;
    const f16* Vth = Vt + (size_t)bh * DH * L_;

    {   // stage bias * log2e: 512 float4 units, exactly one per thread
        const float4 v = ((const float4*)(bias + b * L_))[tid];
        biasl[tid * 4 + 0] = v.x * LOG2E;
        biasl[tid * 4 + 1] = v.y * LOG2E;
        biasl[tid * 4 + 2] = v.z * LOG2E;
        biasl[tid * 4 + 3] = v.w * LOG2E;
    }

    // staging geometry (per 64-key sub-tile):
    // unit p = wave*64 + lane; row r = p>>3, w8 = p&7
    // K source unit = w8 ^ (r&7) ^ (((r>>3)&1)<<2); V source unit = w8 ^ (r&7)
    int krow, kcol, vcol;
    {
        const int p = wave * 64 + lane;
        const int r = p >> 3;
        const int w8 = p & 7;
        krow = r;
        kcol = (w8 ^ (r & 7) ^ (((r >> 3) & 1) << 2)) * 8;
        vcol = (w8 ^ (r & 7)) * 8;
    }

    // Q fragments (B operand of S^T): qf[qtile][dd-half]
    f16x8 qf[2][2];
#pragma unroll
    for (int qt = 0; qt < 2; qt++)
#pragma unroll
        for (int hh = 0; hh < 2; hh++)
            qf[qt][hh] = *(const f16x8*)&Qh[(qrow0 + qt * 16 + l16) * DH + hh * 32 + quad * 8];

    // LDS read offsets for this wave's fixed key-half g (within a sub-tile):
    // tile X rows rX = g*32 + (l16>>2)*8 + (l16&3); tile Y = rX+4.
    int koffX[2], koffY[2], voff[4];
    {
        const int rX = g * 32 + ((l16 >> 2) << 3) + (l16 & 3);
        const int rY = rX + 4;
        const int gkX = (rX & 7) ^ (((rX >> 3) & 1) << 2);
        const int gkY = (rY & 7) ^ (((rY >> 3) & 1) << 2);
#pragma unroll
        for (int hh = 0; hh < 2; hh++) {
            koffX[hh] = rX * 64 + (((hh * 4 + quad) ^ gkX) << 3);
            koffY[hh] = rY * 64 + (((hh * 4 + quad) ^ gkY) << 3);
        }
#pragma unroll
        for (int t = 0; t < 4; t++) {
            const int vr = t * 16 + l16;
            voff[t] = vr * 64 + (((g * 4 + quad) ^ (vr & 7)) << 3);
        }
    }

    // prologue: stage 128-key tile kb=0 into buf 0 (2 K + 2 V loads per wave)
#pragma unroll
    for (int gi = 0; gi < 2; gi++) {
        __builtin_amdgcn_global_load_lds(
            (gu32*)(Kh + (size_t)(gi * 64 + krow) * DH + kcol),
            (su32*)&Ks[0][gi][wave * 512], 16, 0, 0);
        __builtin_amdgcn_global_load_lds(
            (gu32*)(Vth + (size_t)krow * L_ + gi * 64 + vcol),
            (su32*)&Vs[0][gi][wave * 512], 16, 0, 0);
    }

    f32x4 o[2][4] = {};      // partial O^T (this key-half): [qtile][ddtile]
    f32x4 osum[2] = {};      // partial softmax denominator
    const f16x8 ones8 = { (f16)1.f, (f16)1.f, (f16)1.f, (f16)1.f,
                          (f16)1.f, (f16)1.f, (f16)1.f, (f16)1.f };
    __syncthreads();         // drains prologue staging + biasl

#pragma unroll 1
    for (int kb = 0; kb < L_; kb += 128) {
        const int buf = (kb >> 7) & 1;
        const int nkb = (kb + 128 < L_) ? kb + 128 : 0;   // last prefetch harmless

        // prefetch next 128-key tile into buf^1 (async, drained by end barrier)
#pragma unroll
        for (int gi = 0; gi < 2; gi++) {
            __builtin_amdgcn_global_load_lds(
                (gu32*)(Kh + (size_t)(nkb + gi * 64 + krow) * DH + kcol),
                (su32*)&Ks[buf ^ 1][gi][wave * 512], 16, 0, 0);
            __builtin_amdgcn_global_load_lds(
                (gu32*)(Vth + (size_t)krow * L_ + nkb + gi * 64 + vcol),
                (su32*)&Vs[buf ^ 1][gi][wave * 512], 16, 0, 0);
        }

        // two independent 64-key sub-tiles; this wave's key-half of each
#pragma unroll
        for (int gi = 0; gi < 2; gi++) {
            const f16* Kb = &Ks[buf][gi][0];
            const f16* Vb = &Vs[buf][gi][0];
            const f16x8 kx0 = *(const f16x8*)&Kb[koffX[0]];
            const f16x8 kx1 = *(const f16x8*)&Kb[koffX[1]];
            const f16x8 ky0 = *(const f16x8*)&Kb[koffY[0]];
            const f16x8 ky1 = *(const f16x8*)&Kb[koffY[1]];
            f16x8 va[4];
#pragma unroll
            for (int t = 0; t < 4; t++)
                va[t] = *(const f16x8*)&Vb[voff[t]];
            const f32x4 blvX = *(const f32x4*)&biasl[kb + gi * 64 + g * 32 + quad * 8];
            const f32x4 blvY = *(const f32x4*)&biasl[kb + gi * 64 + g * 32 + quad * 8 + 4];

#pragma unroll
            for (int qt = 0; qt < 2; qt++) {
                f32x4 zx = blvX, zy = blvY;      // C = bias (per permuted key-row)
                zx = MFMA32(kx0, qf[qt][0], zx);
                zx = MFMA32(kx1, qf[qt][1], zx); // S^T[key=..+quad*8+r][q]+bias
                zy = MFMA32(ky0, qf[qt][0], zy);
                zy = MFMA32(ky1, qf[qt][1], zy); // S^T[key=..+quad*8+4+r][q]+bias
                const f16x8 pb = {
                    (f16)__builtin_amdgcn_exp2f(zx[0]), (f16)__builtin_amdgcn_exp2f(zx[1]),
                    (f16)__builtin_amdgcn_exp2f(zx[2]), (f16)__builtin_amdgcn_exp2f(zx[3]),
                    (f16)__builtin_amdgcn_exp2f(zy[0]), (f16)__builtin_amdgcn_exp2f(zy[1]),
                    (f16)__builtin_amdgcn_exp2f(zy[2]), (f16)__builtin_amdgcn_exp2f(zy[3]) };
                // P^T B-frag: k=quad*8+j over this wave's 32 keys of sub-tile gi
#pragma unroll
                for (int t = 0; t < 4; t++)
                    o[qt][t] = MFMA32(va[t], pb, o[qt][t]);
                osum[qt] = MFMA32(ones8, pb, osum[qt]);   // denominator colsum
            }
        }
        __syncthreads();   // staged tile ready; reads of buf done
    }
    // (final __syncthreads drained the wrap prefetch -> K/V LDS is dead)

    // cross-wave reduction: key-half g=1 publishes partials via dead LDS.
    float* o0 = (float*)Ks;
    float* o1 = (float*)Vs;
    if (g) {
#pragma unroll
        for (int t = 0; t < 4; t++)
#pragma unroll
            for (int r = 0; r < 4; r++) {
                o0[(qg * 16 + t * 4 + r) * 64 + lane] = o[0][t][r];
                o1[(qg * 16 + t * 4 + r) * 64 + lane] = o[1][t][r];
            }
        biasl[(qg * 64 + lane) * 2 + 0] = osum[0][0];
        biasl[(qg * 64 + lane) * 2 + 1] = osum[1][0];
    }
    __syncthreads();
    if (!g) {
#pragma unroll
        for (int t = 0; t < 4; t++)
#pragma unroll
            for (int r = 0; r < 4; r++) {
                o[0][t][r] += o0[(qg * 16 + t * 4 + r) * 64 + lane];
                o[1][t][r] += o1[(qg * 16 + t * 4 + r) * 64 + lane];
            }
        const float s0 = osum[0][0] + biasl[(qg * 64 + lane) * 2 + 0];
        const float s1 = osum[1][0] + biasl[(qg * 64 + lane) * 2 + 1];
#pragma unroll
        for (int qt = 0; qt < 2; qt++) {
            const float inv = 1.0f / (qt ? s1 : s0);
            const size_t qrow = (size_t)b * L_ + qrow0 + qt * 16 + l16;
#pragma unroll
            for (int t = 0; t < 4; t++) {
                f16x4 pk;
#pragma unroll
                for (int r = 0; r < 4; r++) pk[r] = (f16)(o[qt][t][r] * inv);
                *(f16x4*)&X[qrow * HIDDEN + h * DH + t * 16 + quad * 4] = pk;
            }
        }
    }
}

extern "C" void kernel_launch(void* const* d_in, const int* in_sizes, int n_in,
                              void* d_out, int out_size, void* d_ws, size_t ws_size,
                              hipStream_t stream)
{
    const float* query = (const float*)d_in[0];
    const float* bias  = (const float*)d_in[1];
    const float* Wq = (const float*)d_in[2]; const float* bq = (const float*)d_in[3];
    const float* Wk = (const float*)d_in[4]; const float* bk = (const float*)d_in[5];
    const float* Wv = (const float*)d_in[6]; const float* bv = (const float*)d_in[7];
    const float* Wo = (const float*)d_in[8]; const float* bo = (const float*)d_in[9];
    float* out = (float*)d_out;

    // workspace layout (40 MiB):
    f16* Wh = (f16*)d_ws;           // [4096][1024] packed f16 weights (q,k,v,o rows)
    f16* Qh = Wh + 4096 * 1024;     // [4096][1024] query f16; reused as Xf after qkv
    f16* Kf = Qh + ELEMS;           // [B,H,L,64]
    f16* Vf = Kf + ELEMS;           // [B,H,64,L] transposed
    f16* Qf = Vf + ELEMS;           // [B,H,L,64] scaled
    f16* Xf = Qh;                   // alias: query f16 dead after proj_qkv

    convert_f16<<<2048, 256, 0, stream>>>(query, Wq, Wk, Wv, Wo, Qh, Wh);
    // dynamic LDS: 3*(TM+TN)*32 f16 = 3*(128+128)*32*2 = 49152 B
    proj_qkv<<<dim3(32, 24), 256, 49152, stream>>>(Qh, Wh, bq, bk, bv, Qf, Kf, Vf);
    attn<<<512, 512, 0, stream>>>(Qf, Kf, Vf, bias, Xf);
    // 3*(128+64)*32*2 = 36864 B
    proj_out<<<dim3(32, 16), 256, 36864, stream>>>(Xf, Wh + 3072 * 1024, bo, out);
}